// Round 1
// baseline (2361.703 us; speedup 1.0000x reference)
//
#include <hip/hip_runtime.h>

#define N_NODES 50000
#define N_EDGES 800000

__device__ __forceinline__ float sigf(float v) {
  return __builtin_amdgcn_rcpf(1.0f + __expf(-v));
}

// ---- scatter: agg[dst] += feat[src], row width D floats (D = 64 or 32) ----
template<int D>
__global__ __launch_bounds__(256) void scatter_kernel(
    const float* __restrict__ feat, const int* __restrict__ src,
    const int* __restrict__ dst, float* __restrict__ agg)
{
  constexpr int D4 = D / 4;
  int idx = blockIdx.x * 256 + threadIdx.x;
  if (idx >= N_EDGES * D4) return;
  int e = idx / D4;
  int c = idx % D4;
  int s = src[e], d = dst[e];
  float4 v = ((const float4*)feat)[s * D4 + c];
  float* o = agg + (size_t)d * D + c * 4;
  unsafeAtomicAdd(o + 0, v.x);
  unsafeAtomicAdd(o + 1, v.y);
  unsafeAtomicAdd(o + 2, v.z);
  unsafeAtomicAdd(o + 3, v.w);
}

// ---- node layer 1: t = x + agg; h1 = sig(t@Wn1 + bn1) [128];
//      Q2 = h1@Wn2 [64]; P1 = h1@Wc1 [64]. Block = 256 thr = 4 waves,
//      64 nodes/block (lane = node), waves split output columns. ----
__global__ __launch_bounds__(256) void node1_kernel(
    const float* __restrict__ x, const float* __restrict__ agg,
    const float* __restrict__ Wn1, const float* __restrict__ bn1,
    const float* __restrict__ Wn2, const float* __restrict__ Wc1,
    float* __restrict__ Q2, float* __restrict__ P1)
{
  __shared__ __align__(16) float h1buf[64 * 132];  // [lane][132] padded
  int lane = threadIdx.x & 63;
  int w = __builtin_amdgcn_readfirstlane(threadIdx.x >> 6);
  int node = blockIdx.x * 64 + lane;
  int nc = node < N_NODES ? node : N_NODES - 1;
  const float4* xr = (const float4*)(x + (size_t)nc * 64);
  const float4* gr = (const float4*)(agg + (size_t)nc * 64);
  float t[64];
#pragma unroll
  for (int i4 = 0; i4 < 16; ++i4) {
    float4 xv = xr[i4], gv = gr[i4];
    t[i4*4+0] = xv.x + gv.x; t[i4*4+1] = xv.y + gv.y;
    t[i4*4+2] = xv.z + gv.z; t[i4*4+3] = xv.w + gv.w;
  }
  // phase 1: this wave computes h1 columns [w*32, w*32+32)
  int jb = w * 32;
  float a[32];
#pragma unroll
  for (int j = 0; j < 32; ++j) a[j] = bn1[jb + j];
#pragma unroll
  for (int i = 0; i < 64; ++i) {
    float ti = t[i];
    const float* wr = Wn1 + i * 128 + jb;   // wave-uniform -> s_load
#pragma unroll
    for (int j = 0; j < 32; ++j) a[j] += ti * wr[j];
  }
#pragma unroll
  for (int j4 = 0; j4 < 8; ++j4) {
    float4 hv;
    hv.x = sigf(a[j4*4+0]); hv.y = sigf(a[j4*4+1]);
    hv.z = sigf(a[j4*4+2]); hv.w = sigf(a[j4*4+3]);
    *(float4*)&h1buf[lane * 132 + jb + j4 * 4] = hv;
  }
  __syncthreads();
  // phase 2: this wave computes Q2 & P1 columns [w*16, w*16+16)
  int cb = w * 16;
  float q[16], p[16];
#pragma unroll
  for (int j = 0; j < 16; ++j) { q[j] = 0.f; p[j] = 0.f; }
#pragma unroll 4
  for (int i4 = 0; i4 < 32; ++i4) {
    float4 h = *(const float4*)&h1buf[lane * 132 + i4 * 4];
    float hv[4] = {h.x, h.y, h.z, h.w};
#pragma unroll
    for (int k = 0; k < 4; ++k) {
      const float* w2 = Wn2 + (i4 * 4 + k) * 64 + cb;
      const float* wc = Wc1 + (i4 * 4 + k) * 64 + cb;
      float hk = hv[k];
#pragma unroll
      for (int j = 0; j < 16; ++j) { q[j] += hk * w2[j]; p[j] += hk * wc[j]; }
    }
  }
  if (node < N_NODES) {
    float* qo = Q2 + (size_t)node * 64 + cb;
    float* po = P1 + (size_t)node * 64 + cb;
#pragma unroll
    for (int j4 = 0; j4 < 4; ++j4) {
      *(float4*)(qo + j4*4) = make_float4(q[j4*4], q[j4*4+1], q[j4*4+2], q[j4*4+3]);
      *(float4*)(po + j4*4) = make_float4(p[j4*4], p[j4*4+1], p[j4*4+2], p[j4*4+3]);
    }
  }
}

// ---- node layer 2: h2 = sig(Q2 + agg + bn2) [64];
//      Q3 = h2@Wn3 [32]; P2 = h2@Wc2 [32]. One thread per node. ----
__global__ __launch_bounds__(256) void node2_kernel(
    const float* __restrict__ Q2, const float* __restrict__ agg,
    const float* __restrict__ bn2, const float* __restrict__ Wn3,
    const float* __restrict__ Wc2, float* __restrict__ Q3, float* __restrict__ P2)
{
  int n = blockIdx.x * 256 + threadIdx.x;
  if (n >= N_NODES) return;
  const float4* qr = (const float4*)(Q2 + (size_t)n * 64);
  const float4* gr = (const float4*)(agg + (size_t)n * 64);
  float h[64];
#pragma unroll
  for (int i4 = 0; i4 < 16; ++i4) {
    float4 q = qr[i4], g = gr[i4];
    h[i4*4+0] = sigf(q.x + g.x + bn2[i4*4+0]);
    h[i4*4+1] = sigf(q.y + g.y + bn2[i4*4+1]);
    h[i4*4+2] = sigf(q.z + g.z + bn2[i4*4+2]);
    h[i4*4+3] = sigf(q.w + g.w + bn2[i4*4+3]);
  }
  float a[32];
#pragma unroll
  for (int j = 0; j < 32; ++j) a[j] = 0.f;
#pragma unroll
  for (int i = 0; i < 64; ++i) {
    float hi = h[i];
    const float* wr = Wn3 + i * 32;
#pragma unroll
    for (int j = 0; j < 32; ++j) a[j] += hi * wr[j];
  }
  float* qo = Q3 + (size_t)n * 32;
#pragma unroll
  for (int j4 = 0; j4 < 8; ++j4)
    *(float4*)(qo + j4*4) = make_float4(a[j4*4], a[j4*4+1], a[j4*4+2], a[j4*4+3]);
#pragma unroll
  for (int j = 0; j < 32; ++j) a[j] = 0.f;
#pragma unroll
  for (int i = 0; i < 64; ++i) {
    float hi = h[i];
    const float* wr = Wc2 + i * 32;
#pragma unroll
    for (int j = 0; j < 32; ++j) a[j] += hi * wr[j];
  }
  float* po = P2 + (size_t)n * 32;
#pragma unroll
  for (int j4 = 0; j4 < 8; ++j4)
    *(float4*)(po + j4*4) = make_float4(a[j4*4], a[j4*4+1], a[j4*4+2], a[j4*4+3]);
}

// ---- node layer 3: h3 = sig(Q3 + agg + bn3) [32]; P3 = h3 @ Wc3 [1]. ----
__global__ __launch_bounds__(256) void node3_kernel(
    const float* __restrict__ Q3, const float* __restrict__ agg,
    const float* __restrict__ bn3, const float* __restrict__ Wc3,
    float* __restrict__ P3)
{
  int n = blockIdx.x * 256 + threadIdx.x;
  if (n >= N_NODES) return;
  const float4* qr = (const float4*)(Q3 + (size_t)n * 32);
  const float4* gr = (const float4*)(agg + (size_t)n * 32);
  float acc = 0.f;
#pragma unroll
  for (int i4 = 0; i4 < 8; ++i4) {
    float4 q = qr[i4], g = gr[i4];
    acc += sigf(q.x + g.x + bn3[i4*4+0]) * Wc3[i4*4+0];
    acc += sigf(q.y + g.y + bn3[i4*4+1]) * Wc3[i4*4+1];
    acc += sigf(q.z + g.z + bn3[i4*4+2]) * Wc3[i4*4+2];
    acc += sigf(q.w + g.w + bn3[i4*4+3]) * Wc3[i4*4+3];
  }
  P3[n] = acc;
}

// ---- edge kernel: per edge e:
//   c1 = sig(P1[s]+P1[d]+bc1) [64]; c2 = sig(P2[s]+P2[d]+bc2) [32]
//   g1 = sig(c1@Wg1 + bg1 + c2) [32]; c3 = sig(P3[s]+P3[d]+bc3)
//   out = sig(g1@Wg2 + bg2 + c3)
// Block = 128 (2 waves), each wave stages 64 edges in LDS then lane=edge. ----
__global__ __launch_bounds__(128) void edge_kernel(
    const int* __restrict__ src, const int* __restrict__ dst,
    const float* __restrict__ P1, const float* __restrict__ P2,
    const float* __restrict__ P3,
    const float* __restrict__ bc1, const float* __restrict__ bc2,
    const float* __restrict__ bc3,
    const float* __restrict__ Wg1, const float* __restrict__ bg1,
    const float* __restrict__ Wg2, const float* __restrict__ bg2,
    float* __restrict__ out)
{
  __shared__ float sbuf[2 * 64 * 101];   // [wave][edge][101]: c1(64) c2(32) c3(1)
  int lane = threadIdx.x & 63;
  int w = __builtin_amdgcn_readfirstlane(threadIdx.x >> 6);
  int ebase = (blockIdx.x * 2 + w) * 64;
  float* wb = sbuf + w * 64 * 101;
  float bc1v = bc1[lane];
  float bc2v = bc2[lane & 31];
  // phase A: stage c1/c2/c3 for 64 edges (coalesced P-row reads, s/d via s_load)
#pragma unroll 4
  for (int e = 0; e < 64; ++e) {
    int s = src[ebase + e];
    int d = dst[ebase + e];
    float c1v = sigf(P1[(size_t)s * 64 + lane] + P1[(size_t)d * 64 + lane] + bc1v);
    wb[e * 101 + lane] = c1v;
    if (lane < 32) {
      float c2v = sigf(P2[(size_t)s * 32 + lane] + P2[(size_t)d * 32 + lane] + bc2v);
      wb[e * 101 + 64 + lane] = c2v;
    }
    if (lane == 0) wb[e * 101 + 96] = P3[s] + P3[d];
  }
  __syncthreads();
  // phase B: lane = edge
  const float* myrow = wb + lane * 101;
  float a[32];
#pragma unroll
  for (int j = 0; j < 32; ++j) a[j] = bg1[j] + myrow[64 + j];
#pragma unroll 8
  for (int i = 0; i < 64; ++i) {
    float ci = myrow[i];
#pragma unroll
    for (int j = 0; j < 32; ++j) a[j] += ci * Wg1[i * 32 + j];  // s_load weights
  }
  float c3v = sigf(myrow[96] + bc3[0]);
  float oacc = 0.f;
#pragma unroll
  for (int j = 0; j < 32; ++j) oacc += sigf(a[j]) * Wg2[j];
  out[ebase + lane] = sigf(oacc + bg2[0] + c3v);
}

extern "C" void kernel_launch(void* const* d_in, const int* in_sizes, int n_in,
                              void* d_out, int out_size, void* d_ws, size_t ws_size,
                              hipStream_t stream)
{
  const float* x   = (const float*)d_in[0];
  const int*   src = (const int*)d_in[1];
  const int*   dst = (const int*)d_in[2];
  const float* Wn1 = (const float*)d_in[3];
  const float* bn1 = (const float*)d_in[4];
  const float* Wc1 = (const float*)d_in[5];
  const float* bc1 = (const float*)d_in[6];
  const float* Wn2 = (const float*)d_in[7];
  const float* bn2 = (const float*)d_in[8];
  const float* Wc2 = (const float*)d_in[9];
  const float* bc2 = (const float*)d_in[10];
  const float* Wn3 = (const float*)d_in[11];
  const float* bn3 = (const float*)d_in[12];
  const float* Wc3 = (const float*)d_in[13];
  const float* bc3 = (const float*)d_in[14];
  const float* Wg1 = (const float*)d_in[15];
  const float* bg1 = (const float*)d_in[16];
  const float* Wg2 = (const float*)d_in[17];
  const float* bg2 = (const float*)d_in[18];
  float* out = (float*)d_out;

  float* ws  = (float*)d_ws;
  float* AGG = ws;                           // N*64 (reused for all 3 layers)
  float* Q2  = AGG + (size_t)N_NODES * 64;   // N*64
  float* P1  = Q2  + (size_t)N_NODES * 64;   // N*64
  float* Q3  = P1  + (size_t)N_NODES * 64;   // N*32
  float* P2  = Q3  + (size_t)N_NODES * 32;   // N*32
  float* P3  = P2  + (size_t)N_NODES * 32;   // N*1

  // layer 1: AGG = segsum(x[src]); node1 -> Q2, P1
  hipMemsetAsync(AGG, 0, (size_t)N_NODES * 64 * sizeof(float), stream);
  scatter_kernel<64><<<(N_EDGES * 16 + 255) / 256, 256, 0, stream>>>(x, src, dst, AGG);
  node1_kernel<<<(N_NODES + 63) / 64, 256, 0, stream>>>(x, AGG, Wn1, bn1, Wn2, Wc1, Q2, P1);
  // layer 2: AGG = segsum(Q2[src]); node2 -> Q3, P2
  hipMemsetAsync(AGG, 0, (size_t)N_NODES * 64 * sizeof(float), stream);
  scatter_kernel<64><<<(N_EDGES * 16 + 255) / 256, 256, 0, stream>>>(Q2, src, dst, AGG);
  node2_kernel<<<(N_NODES + 255) / 256, 256, 0, stream>>>(Q2, AGG, bn2, Wn3, Wc2, Q3, P2);
  // layer 3: AGG = segsum(Q3[src]); node3 -> P3
  hipMemsetAsync(AGG, 0, (size_t)N_NODES * 32 * sizeof(float), stream);
  scatter_kernel<32><<<(N_EDGES * 8 + 255) / 256, 256, 0, stream>>>(Q3, src, dst, AGG);
  node3_kernel<<<(N_NODES + 255) / 256, 256, 0, stream>>>(Q3, AGG, bn3, Wc3, P3);
  // edge-level epilogue
  edge_kernel<<<N_EDGES / 128, 128, 0, stream>>>(src, dst, P1, P2, P3,
      bc1, bc2, bc3, Wg1, bg1, Wg2, bg2, out);
}

// Round 2
// 904.873 us; speedup vs baseline: 2.6100x; 2.6100x over previous
//
#include <hip/hip_runtime.h>

#define N_NODES 50000
#define N_EDGES 800000

__device__ __forceinline__ float sigf(float v) {
  return __builtin_amdgcn_rcpf(1.0f + __expf(-v));
}

// ---- CSR build: histogram of dst ----
__global__ __launch_bounds__(256) void hist_kernel(
    const int* __restrict__ dst, int* __restrict__ cnt)
{
  int e = blockIdx.x * 256 + threadIdx.x;
  if (e < N_EDGES) atomicAdd(&cnt[dst[e]], 1);
}

// ---- CSR build: single-block exclusive scan over counts ->
//      rowptr[N+1], cursor[N] (= exclusive prefix) ----
__global__ __launch_bounds__(1024) void scan_kernel(
    const int* __restrict__ cnt, int* __restrict__ rowptr,
    int* __restrict__ cursor)
{
  __shared__ int wsum[16];
  int tid = threadIdx.x, lane = tid & 63, w = tid >> 6;
  int carry = 0;
  if (tid == 0) rowptr[0] = 0;
  for (int base = 0; base < N_NODES; base += 1024) {
    int i = base + tid;
    int v = (i < N_NODES) ? cnt[i] : 0;
    // wave inclusive scan
    int x = v;
#pragma unroll
    for (int off = 1; off < 64; off <<= 1) {
      int y = __shfl_up(x, off);
      if (lane >= off) x += y;
    }
    if (lane == 63) wsum[w] = x;
    __syncthreads();
    if (w == 0 && lane < 16) {
      int s = wsum[lane];
#pragma unroll
      for (int off = 1; off < 16; off <<= 1) {
        int y = __shfl_up(s, off);
        if (lane >= off) s += y;
      }
      wsum[lane] = s;
    }
    __syncthreads();
    int woff = (w == 0) ? 0 : wsum[w - 1];
    int incl = x + woff + carry;
    if (i < N_NODES) {
      rowptr[i + 1] = incl;
      cursor[i] = incl - v;
    }
    carry += wsum[15];
    __syncthreads();
  }
}

// ---- CSR build: scatter src indices into dst-sorted order ----
__global__ __launch_bounds__(256) void fill_kernel(
    const int* __restrict__ src, const int* __restrict__ dst,
    int* __restrict__ cursor, int* __restrict__ col)
{
  int e = blockIdx.x * 256 + threadIdx.x;
  if (e >= N_EDGES) return;
  int pos = atomicAdd(&cursor[dst[e]], 1);
  col[pos] = src[e];
}

// ---- gather aggregation: agg[n] = sum over incoming edges of feat[col[k]] ----
template<int D>
__global__ __launch_bounds__(256) void gather_agg(
    const float* __restrict__ feat, const int* __restrict__ rowptr,
    const int* __restrict__ col, float* __restrict__ agg)
{
  int w = __builtin_amdgcn_readfirstlane(threadIdx.x >> 6);
  int lane = threadIdx.x & 63;
  int n = blockIdx.x * 4 + w;
  if (n >= N_NODES) return;
  int beg = rowptr[n], end = rowptr[n + 1];
  if (D == 64) {
    float acc = 0.f;
    int k = beg;
    for (; k + 1 < end; k += 2) {
      int s0 = col[k], s1 = col[k + 1];            // wave-uniform -> s_load
      float v0 = feat[(size_t)s0 * 64 + lane];
      float v1 = feat[(size_t)s1 * 64 + lane];
      acc += v0 + v1;
    }
    if (k < end) acc += feat[(size_t)col[k] * 64 + lane];
    agg[(size_t)n * 64 + lane] = acc;
  } else {  // D == 32: half-waves take alternating edges
    int half = lane >> 5, c = lane & 31;
    float acc = 0.f;
    int k = beg + half;
    for (; k + 2 < end; k += 4) {
      float v0 = feat[(size_t)col[k] * 32 + c];
      float v1 = feat[(size_t)col[k + 2] * 32 + c];
      acc += v0 + v1;
    }
    if (k < end) acc += feat[(size_t)col[k] * 32 + c];
    acc += __shfl_xor(acc, 32);
    if (half == 0) agg[(size_t)n * 32 + c] = acc;
  }
}

// ---- node layer 1: t = x + agg; h1 = sig(t@Wn1 + bn1) [128];
//      Q2 = h1@Wn2 [64]; P1 = h1@Wc1 [64]. ----
__global__ __launch_bounds__(256) void node1_kernel(
    const float* __restrict__ x, const float* __restrict__ agg,
    const float* __restrict__ Wn1, const float* __restrict__ bn1,
    const float* __restrict__ Wn2, const float* __restrict__ Wc1,
    float* __restrict__ Q2, float* __restrict__ P1)
{
  __shared__ __align__(16) float h1buf[64 * 132];  // [lane][132] padded
  int lane = threadIdx.x & 63;
  int w = __builtin_amdgcn_readfirstlane(threadIdx.x >> 6);
  int node = blockIdx.x * 64 + lane;
  int nc = node < N_NODES ? node : N_NODES - 1;
  const float4* xr = (const float4*)(x + (size_t)nc * 64);
  const float4* gr = (const float4*)(agg + (size_t)nc * 64);
  float t[64];
#pragma unroll
  for (int i4 = 0; i4 < 16; ++i4) {
    float4 xv = xr[i4], gv = gr[i4];
    t[i4*4+0] = xv.x + gv.x; t[i4*4+1] = xv.y + gv.y;
    t[i4*4+2] = xv.z + gv.z; t[i4*4+3] = xv.w + gv.w;
  }
  int jb = w * 32;
  float a[32];
#pragma unroll
  for (int j = 0; j < 32; ++j) a[j] = bn1[jb + j];
#pragma unroll
  for (int i = 0; i < 64; ++i) {
    float ti = t[i];
    const float* wr = Wn1 + i * 128 + jb;   // wave-uniform -> s_load
#pragma unroll
    for (int j = 0; j < 32; ++j) a[j] += ti * wr[j];
  }
#pragma unroll
  for (int j4 = 0; j4 < 8; ++j4) {
    float4 hv;
    hv.x = sigf(a[j4*4+0]); hv.y = sigf(a[j4*4+1]);
    hv.z = sigf(a[j4*4+2]); hv.w = sigf(a[j4*4+3]);
    *(float4*)&h1buf[lane * 132 + jb + j4 * 4] = hv;
  }
  __syncthreads();
  int cb = w * 16;
  float q[16], p[16];
#pragma unroll
  for (int j = 0; j < 16; ++j) { q[j] = 0.f; p[j] = 0.f; }
#pragma unroll 4
  for (int i4 = 0; i4 < 32; ++i4) {
    float4 h = *(const float4*)&h1buf[lane * 132 + i4 * 4];
    float hv[4] = {h.x, h.y, h.z, h.w};
#pragma unroll
    for (int k = 0; k < 4; ++k) {
      const float* w2 = Wn2 + (i4 * 4 + k) * 64 + cb;
      const float* wc = Wc1 + (i4 * 4 + k) * 64 + cb;
      float hk = hv[k];
#pragma unroll
      for (int j = 0; j < 16; ++j) { q[j] += hk * w2[j]; p[j] += hk * wc[j]; }
    }
  }
  if (node < N_NODES) {
    float* qo = Q2 + (size_t)node * 64 + cb;
    float* po = P1 + (size_t)node * 64 + cb;
#pragma unroll
    for (int j4 = 0; j4 < 4; ++j4) {
      *(float4*)(qo + j4*4) = make_float4(q[j4*4], q[j4*4+1], q[j4*4+2], q[j4*4+3]);
      *(float4*)(po + j4*4) = make_float4(p[j4*4], p[j4*4+1], p[j4*4+2], p[j4*4+3]);
    }
  }
}

// ---- node layer 2 ----
__global__ __launch_bounds__(256) void node2_kernel(
    const float* __restrict__ Q2, const float* __restrict__ agg,
    const float* __restrict__ bn2, const float* __restrict__ Wn3,
    const float* __restrict__ Wc2, float* __restrict__ Q3, float* __restrict__ P2)
{
  int n = blockIdx.x * 256 + threadIdx.x;
  if (n >= N_NODES) return;
  const float4* qr = (const float4*)(Q2 + (size_t)n * 64);
  const float4* gr = (const float4*)(agg + (size_t)n * 64);
  float h[64];
#pragma unroll
  for (int i4 = 0; i4 < 16; ++i4) {
    float4 q = qr[i4], g = gr[i4];
    h[i4*4+0] = sigf(q.x + g.x + bn2[i4*4+0]);
    h[i4*4+1] = sigf(q.y + g.y + bn2[i4*4+1]);
    h[i4*4+2] = sigf(q.z + g.z + bn2[i4*4+2]);
    h[i4*4+3] = sigf(q.w + g.w + bn2[i4*4+3]);
  }
  float a[32];
#pragma unroll
  for (int j = 0; j < 32; ++j) a[j] = 0.f;
#pragma unroll
  for (int i = 0; i < 64; ++i) {
    float hi = h[i];
    const float* wr = Wn3 + i * 32;
#pragma unroll
    for (int j = 0; j < 32; ++j) a[j] += hi * wr[j];
  }
  float* qo = Q3 + (size_t)n * 32;
#pragma unroll
  for (int j4 = 0; j4 < 8; ++j4)
    *(float4*)(qo + j4*4) = make_float4(a[j4*4], a[j4*4+1], a[j4*4+2], a[j4*4+3]);
#pragma unroll
  for (int j = 0; j < 32; ++j) a[j] = 0.f;
#pragma unroll
  for (int i = 0; i < 64; ++i) {
    float hi = h[i];
    const float* wr = Wc2 + i * 32;
#pragma unroll
    for (int j = 0; j < 32; ++j) a[j] += hi * wr[j];
  }
  float* po = P2 + (size_t)n * 32;
#pragma unroll
  for (int j4 = 0; j4 < 8; ++j4)
    *(float4*)(po + j4*4) = make_float4(a[j4*4], a[j4*4+1], a[j4*4+2], a[j4*4+3]);
}

// ---- node layer 3 ----
__global__ __launch_bounds__(256) void node3_kernel(
    const float* __restrict__ Q3, const float* __restrict__ agg,
    const float* __restrict__ bn3, const float* __restrict__ Wc3,
    float* __restrict__ P3)
{
  int n = blockIdx.x * 256 + threadIdx.x;
  if (n >= N_NODES) return;
  const float4* qr = (const float4*)(Q3 + (size_t)n * 32);
  const float4* gr = (const float4*)(agg + (size_t)n * 32);
  float acc = 0.f;
#pragma unroll
  for (int i4 = 0; i4 < 8; ++i4) {
    float4 q = qr[i4], g = gr[i4];
    acc += sigf(q.x + g.x + bn3[i4*4+0]) * Wc3[i4*4+0];
    acc += sigf(q.y + g.y + bn3[i4*4+1]) * Wc3[i4*4+1];
    acc += sigf(q.z + g.z + bn3[i4*4+2]) * Wc3[i4*4+2];
    acc += sigf(q.w + g.w + bn3[i4*4+3]) * Wc3[i4*4+3];
  }
  P3[n] = acc;
}

// ---- edge kernel ----
__global__ __launch_bounds__(128) void edge_kernel(
    const int* __restrict__ src, const int* __restrict__ dst,
    const float* __restrict__ P1, const float* __restrict__ P2,
    const float* __restrict__ P3,
    const float* __restrict__ bc1, const float* __restrict__ bc2,
    const float* __restrict__ bc3,
    const float* __restrict__ Wg1, const float* __restrict__ bg1,
    const float* __restrict__ Wg2, const float* __restrict__ bg2,
    float* __restrict__ out)
{
  __shared__ float sbuf[2 * 64 * 101];   // [wave][edge][101]: c1(64) c2(32) c3(1)
  int lane = threadIdx.x & 63;
  int w = __builtin_amdgcn_readfirstlane(threadIdx.x >> 6);
  int ebase = (blockIdx.x * 2 + w) * 64;
  float* wb = sbuf + w * 64 * 101;
  float bc1v = bc1[lane];
  float bc2v = bc2[lane & 31];
#pragma unroll 4
  for (int e = 0; e < 64; ++e) {
    int s = src[ebase + e];
    int d = dst[ebase + e];
    float c1v = sigf(P1[(size_t)s * 64 + lane] + P1[(size_t)d * 64 + lane] + bc1v);
    wb[e * 101 + lane] = c1v;
    if (lane < 32) {
      float c2v = sigf(P2[(size_t)s * 32 + lane] + P2[(size_t)d * 32 + lane] + bc2v);
      wb[e * 101 + 64 + lane] = c2v;
    }
    if (lane == 0) wb[e * 101 + 96] = P3[s] + P3[d];
  }
  __syncthreads();
  const float* myrow = wb + lane * 101;
  float a[32];
#pragma unroll
  for (int j = 0; j < 32; ++j) a[j] = bg1[j] + myrow[64 + j];
#pragma unroll 8
  for (int i = 0; i < 64; ++i) {
    float ci = myrow[i];
#pragma unroll
    for (int j = 0; j < 32; ++j) a[j] += ci * Wg1[i * 32 + j];
  }
  float c3v = sigf(myrow[96] + bc3[0]);
  float oacc = 0.f;
#pragma unroll
  for (int j = 0; j < 32; ++j) oacc += sigf(a[j]) * Wg2[j];
  out[ebase + lane] = sigf(oacc + bg2[0] + c3v);
}

extern "C" void kernel_launch(void* const* d_in, const int* in_sizes, int n_in,
                              void* d_out, int out_size, void* d_ws, size_t ws_size,
                              hipStream_t stream)
{
  const float* x   = (const float*)d_in[0];
  const int*   src = (const int*)d_in[1];
  const int*   dst = (const int*)d_in[2];
  const float* Wn1 = (const float*)d_in[3];
  const float* bn1 = (const float*)d_in[4];
  const float* Wc1 = (const float*)d_in[5];
  const float* bc1 = (const float*)d_in[6];
  const float* Wn2 = (const float*)d_in[7];
  const float* bn2 = (const float*)d_in[8];
  const float* Wc2 = (const float*)d_in[9];
  const float* bc2 = (const float*)d_in[10];
  const float* Wn3 = (const float*)d_in[11];
  const float* bn3 = (const float*)d_in[12];
  const float* Wc3 = (const float*)d_in[13];
  const float* bc3 = (const float*)d_in[14];
  const float* Wg1 = (const float*)d_in[15];
  const float* bg1 = (const float*)d_in[16];
  const float* Wg2 = (const float*)d_in[17];
  const float* bg2 = (const float*)d_in[18];
  float* out = (float*)d_out;

  float* ws  = (float*)d_ws;
  float* AGG = ws;                           // N*64 (reused for all 3 layers)
  float* Q2  = AGG + (size_t)N_NODES * 64;   // N*64
  float* P1  = Q2  + (size_t)N_NODES * 64;   // N*64
  float* Q3  = P1  + (size_t)N_NODES * 64;   // N*32
  float* P2  = Q3  + (size_t)N_NODES * 32;   // N*32
  float* P3  = P2  + (size_t)N_NODES * 32;   // N*1
  int* rowptr = (int*)(P3 + N_NODES);        // N+1
  int* cursor = rowptr + (N_NODES + 1);      // N (doubles as hist counts)
  int* col    = cursor + N_NODES;            // E

  // ---- build CSR by dst (per call; deterministic work) ----
  hipMemsetAsync(cursor, 0, (size_t)N_NODES * sizeof(int), stream);
  hist_kernel<<<N_EDGES / 256, 256, 0, stream>>>(dst, cursor);
  scan_kernel<<<1, 1024, 0, stream>>>(cursor, rowptr, cursor);
  fill_kernel<<<N_EDGES / 256, 256, 0, stream>>>(src, dst, cursor, col);

  // layer 1
  gather_agg<64><<<(N_NODES + 3) / 4, 256, 0, stream>>>(x, rowptr, col, AGG);
  node1_kernel<<<(N_NODES + 63) / 64, 256, 0, stream>>>(x, AGG, Wn1, bn1, Wn2, Wc1, Q2, P1);
  // layer 2
  gather_agg<64><<<(N_NODES + 3) / 4, 256, 0, stream>>>(Q2, rowptr, col, AGG);
  node2_kernel<<<(N_NODES + 255) / 256, 256, 0, stream>>>(Q2, AGG, bn2, Wn3, Wc2, Q3, P2);
  // layer 3
  gather_agg<32><<<(N_NODES + 3) / 4, 256, 0, stream>>>(Q3, rowptr, col, AGG);
  node3_kernel<<<(N_NODES + 255) / 256, 256, 0, stream>>>(Q3, AGG, bn3, Wc3, P3);
  // edge-level epilogue
  edge_kernel<<<N_EDGES / 128, 128, 0, stream>>>(src, dst, P1, P2, P3,
      bc1, bc2, bc3, Wg1, bg1, Wg2, bg2, out);
}

// Round 3
// 500.297 us; speedup vs baseline: 4.7206x; 1.8087x over previous
//
#include <hip/hip_runtime.h>

#define N_NODES 50000
#define N_EDGES 800000

typedef _Float16 h2 __attribute__((ext_vector_type(2)));

__device__ __forceinline__ float sigf(float v) {
  return __builtin_amdgcn_rcpf(1.0f + __expf(-v));
}

__device__ __forceinline__ float fdot2f(h2 a, h2 b, float c) {
#if __has_builtin(__builtin_amdgcn_fdot2)
  return __builtin_amdgcn_fdot2(a, b, c, false);
#else
  return c + (float)a.x * (float)b.x + (float)a.y * (float)b.y;
#endif
}

// ---- CSR build: histogram of dst ----
__global__ __launch_bounds__(256) void hist_kernel(
    const int* __restrict__ dst, int* __restrict__ cnt)
{
  int e = blockIdx.x * 256 + threadIdx.x;
  if (e < N_EDGES) atomicAdd(&cnt[dst[e]], 1);
}

// ---- CSR build: single-block exclusive scan ----
__global__ __launch_bounds__(1024) void scan_kernel(
    const int* __restrict__ cnt, int* __restrict__ rowptr,
    int* __restrict__ cursor)
{
  __shared__ int wsum[16];
  int tid = threadIdx.x, lane = tid & 63, w = tid >> 6;
  int carry = 0;
  if (tid == 0) rowptr[0] = 0;
  for (int base = 0; base < N_NODES; base += 1024) {
    int i = base + tid;
    int v = (i < N_NODES) ? cnt[i] : 0;
    int x = v;
#pragma unroll
    for (int off = 1; off < 64; off <<= 1) {
      int y = __shfl_up(x, off);
      if (lane >= off) x += y;
    }
    if (lane == 63) wsum[w] = x;
    __syncthreads();
    if (w == 0 && lane < 16) {
      int s = wsum[lane];
#pragma unroll
      for (int off = 1; off < 16; off <<= 1) {
        int y = __shfl_up(s, off);
        if (lane >= off) s += y;
      }
      wsum[lane] = s;
    }
    __syncthreads();
    int woff = (w == 0) ? 0 : wsum[w - 1];
    int incl = x + woff + carry;
    if (i < N_NODES) {
      rowptr[i + 1] = incl;
      cursor[i] = incl - v;
    }
    carry += wsum[15];
    __syncthreads();
  }
}

// ---- CSR build: fill column indices ----
__global__ __launch_bounds__(256) void fill_kernel(
    const int* __restrict__ src, const int* __restrict__ dst,
    int* __restrict__ cursor, int* __restrict__ col)
{
  int e = blockIdx.x * 256 + threadIdx.x;
  if (e >= N_EDGES) return;
  int pos = atomicAdd(&cursor[dst[e]], 1);
  col[pos] = src[e];
}

// ---- gather aggregation via readlane (no scalar-mem drains) ----
template<int D>
__global__ __launch_bounds__(256) void gather_agg(
    const float* __restrict__ feat, const int* __restrict__ rowptr,
    const int* __restrict__ col, float* __restrict__ agg)
{
  int w = threadIdx.x >> 6;
  int lane = threadIdx.x & 63;
  int n = blockIdx.x * 4 + w;
  if (n >= N_NODES) return;
  int beg = rowptr[n], end = rowptr[n + 1];
  if (D == 64) {
    float acc0 = 0.f, acc1 = 0.f;
    for (int k0 = beg; k0 < end; k0 += 64) {
      int kk = k0 + lane;
      int cv = (kk < end) ? col[kk] : 0;       // one coalesced load per chunk
      int m = end - k0; if (m > 64) m = 64;
      int e = 0;
      for (; e + 1 < m; e += 2) {
        int s0 = __builtin_amdgcn_readlane(cv, e);
        int s1 = __builtin_amdgcn_readlane(cv, e + 1);
        acc0 += feat[(size_t)s0 * 64 + lane];
        acc1 += feat[(size_t)s1 * 64 + lane];
      }
      if (e < m) {
        int s0 = __builtin_amdgcn_readlane(cv, e);
        acc0 += feat[(size_t)s0 * 64 + lane];
      }
    }
    agg[(size_t)n * 64 + lane] = acc0 + acc1;
  } else {  // D == 32: halves take even/odd edges
    int c = lane & 31, h = lane >> 5;
    float acc = 0.f;
    for (int k0 = beg; k0 < end; k0 += 64) {
      int kk = k0 + lane;
      int cv = (kk < end) ? col[kk] : 0;
      int m = end - k0; if (m > 64) m = 64;
      int e = 0;
      for (; e + 1 < m; e += 2) {
        int s0 = __builtin_amdgcn_readlane(cv, e);
        int s1 = __builtin_amdgcn_readlane(cv, e + 1);
        int sd = h ? s1 : s0;
        acc += feat[(size_t)sd * 32 + c];
      }
      if (e < m) {
        int s0 = __builtin_amdgcn_readlane(cv, e);
        if (h == 0) acc += feat[(size_t)s0 * 32 + c];
      }
    }
    acc += __shfl_xor(acc, 32);
    if (h == 0) agg[(size_t)n * 32 + c] = acc;
  }
}

// ---- node layer 1 ----
__global__ __launch_bounds__(256) void node1_kernel(
    const float* __restrict__ x, const float* __restrict__ agg,
    const float* __restrict__ Wn1, const float* __restrict__ bn1,
    const float* __restrict__ Wn2, const float* __restrict__ Wc1,
    float* __restrict__ Q2, float* __restrict__ P1)
{
  __shared__ __align__(16) float h1buf[64 * 132];
  int lane = threadIdx.x & 63;
  int w = __builtin_amdgcn_readfirstlane(threadIdx.x >> 6);
  int node = blockIdx.x * 64 + lane;
  int nc = node < N_NODES ? node : N_NODES - 1;
  const float4* xr = (const float4*)(x + (size_t)nc * 64);
  const float4* gr = (const float4*)(agg + (size_t)nc * 64);
  float t[64];
#pragma unroll
  for (int i4 = 0; i4 < 16; ++i4) {
    float4 xv = xr[i4], gv = gr[i4];
    t[i4*4+0] = xv.x + gv.x; t[i4*4+1] = xv.y + gv.y;
    t[i4*4+2] = xv.z + gv.z; t[i4*4+3] = xv.w + gv.w;
  }
  int jb = w * 32;
  float a[32];
#pragma unroll
  for (int j = 0; j < 32; ++j) a[j] = bn1[jb + j];
#pragma unroll
  for (int i = 0; i < 64; ++i) {
    float ti = t[i];
    const float* wr = Wn1 + i * 128 + jb;
#pragma unroll
    for (int j = 0; j < 32; ++j) a[j] += ti * wr[j];
  }
#pragma unroll
  for (int j4 = 0; j4 < 8; ++j4) {
    float4 hv;
    hv.x = sigf(a[j4*4+0]); hv.y = sigf(a[j4*4+1]);
    hv.z = sigf(a[j4*4+2]); hv.w = sigf(a[j4*4+3]);
    *(float4*)&h1buf[lane * 132 + jb + j4 * 4] = hv;
  }
  __syncthreads();
  int cb = w * 16;
  float q[16], p[16];
#pragma unroll
  for (int j = 0; j < 16; ++j) { q[j] = 0.f; p[j] = 0.f; }
#pragma unroll 4
  for (int i4 = 0; i4 < 32; ++i4) {
    float4 h = *(const float4*)&h1buf[lane * 132 + i4 * 4];
    float hv[4] = {h.x, h.y, h.z, h.w};
#pragma unroll
    for (int k = 0; k < 4; ++k) {
      const float* w2 = Wn2 + (i4 * 4 + k) * 64 + cb;
      const float* wc = Wc1 + (i4 * 4 + k) * 64 + cb;
      float hk = hv[k];
#pragma unroll
      for (int j = 0; j < 16; ++j) { q[j] += hk * w2[j]; p[j] += hk * wc[j]; }
    }
  }
  if (node < N_NODES) {
    float* qo = Q2 + (size_t)node * 64 + cb;
    float* po = P1 + (size_t)node * 64 + cb;
#pragma unroll
    for (int j4 = 0; j4 < 4; ++j4) {
      *(float4*)(qo + j4*4) = make_float4(q[j4*4], q[j4*4+1], q[j4*4+2], q[j4*4+3]);
      *(float4*)(po + j4*4) = make_float4(p[j4*4], p[j4*4+1], p[j4*4+2], p[j4*4+3]);
    }
  }
}

// ---- node layer 2 ----
__global__ __launch_bounds__(256) void node2_kernel(
    const float* __restrict__ Q2, const float* __restrict__ agg,
    const float* __restrict__ bn2, const float* __restrict__ Wn3,
    const float* __restrict__ Wc2, float* __restrict__ Q3, float* __restrict__ P2)
{
  int n = blockIdx.x * 256 + threadIdx.x;
  if (n >= N_NODES) return;
  const float4* qr = (const float4*)(Q2 + (size_t)n * 64);
  const float4* gr = (const float4*)(agg + (size_t)n * 64);
  float h[64];
#pragma unroll
  for (int i4 = 0; i4 < 16; ++i4) {
    float4 q = qr[i4], g = gr[i4];
    h[i4*4+0] = sigf(q.x + g.x + bn2[i4*4+0]);
    h[i4*4+1] = sigf(q.y + g.y + bn2[i4*4+1]);
    h[i4*4+2] = sigf(q.z + g.z + bn2[i4*4+2]);
    h[i4*4+3] = sigf(q.w + g.w + bn2[i4*4+3]);
  }
  float a[32];
#pragma unroll
  for (int j = 0; j < 32; ++j) a[j] = 0.f;
#pragma unroll
  for (int i = 0; i < 64; ++i) {
    float hi = h[i];
    const float* wr = Wn3 + i * 32;
#pragma unroll
    for (int j = 0; j < 32; ++j) a[j] += hi * wr[j];
  }
  float* qo = Q3 + (size_t)n * 32;
#pragma unroll
  for (int j4 = 0; j4 < 8; ++j4)
    *(float4*)(qo + j4*4) = make_float4(a[j4*4], a[j4*4+1], a[j4*4+2], a[j4*4+3]);
#pragma unroll
  for (int j = 0; j < 32; ++j) a[j] = 0.f;
#pragma unroll
  for (int i = 0; i < 64; ++i) {
    float hi = h[i];
    const float* wr = Wc2 + i * 32;
#pragma unroll
    for (int j = 0; j < 32; ++j) a[j] += hi * wr[j];
  }
  float* po = P2 + (size_t)n * 32;
#pragma unroll
  for (int j4 = 0; j4 < 8; ++j4)
    *(float4*)(po + j4*4) = make_float4(a[j4*4], a[j4*4+1], a[j4*4+2], a[j4*4+3]);
}

// ---- node layer 3 ----
__global__ __launch_bounds__(256) void node3_kernel(
    const float* __restrict__ Q3, const float* __restrict__ agg,
    const float* __restrict__ bn3, const float* __restrict__ Wc3,
    float* __restrict__ P3)
{
  int n = blockIdx.x * 256 + threadIdx.x;
  if (n >= N_NODES) return;
  const float4* qr = (const float4*)(Q3 + (size_t)n * 32);
  const float4* gr = (const float4*)(agg + (size_t)n * 32);
  float acc = 0.f;
#pragma unroll
  for (int i4 = 0; i4 < 8; ++i4) {
    float4 q = qr[i4], g = gr[i4];
    acc += sigf(q.x + g.x + bn3[i4*4+0]) * Wc3[i4*4+0];
    acc += sigf(q.y + g.y + bn3[i4*4+1]) * Wc3[i4*4+1];
    acc += sigf(q.z + g.z + bn3[i4*4+2]) * Wc3[i4*4+2];
    acc += sigf(q.w + g.w + bn3[i4*4+3]) * Wc3[i4*4+3];
  }
  P3[n] = acc;
}

// ---- edge kernel: 256 thr = 4 waves, 32 edges/wave, f16 LDS staging,
//      readlane-driven gathers (no scalar-mem in loops), v_dot2 GEMM ----
__global__ __launch_bounds__(256, 4) void edge_kernel(
    const int* __restrict__ src, const int* __restrict__ dst,
    const float* __restrict__ P1, const float* __restrict__ P2,
    const float* __restrict__ P3,
    const float* __restrict__ bc1, const float* __restrict__ bc2,
    const float* __restrict__ bc3,
    const float* __restrict__ Wg1, const float* __restrict__ bg1,
    const float* __restrict__ Wg2, const float* __restrict__ bg2,
    float* __restrict__ out)
{
  __shared__ unsigned int Wp[1024];            // f16-pair packed Wg1 (16B-aligned)
  __shared__ _Float16 sbuf[128 * 102];         // per-edge rows: c1[64] c2[32] c3, pad 102

  int lane = threadIdx.x & 63;
  int w = threadIdx.x >> 6;
  int ebase = blockIdx.x * 128 + w * 32;
  _Float16* wb = sbuf + w * 32 * 102;

  // stage packed Wg1 (all threads)
  for (int idx = threadIdx.x; idx < 1024; idx += 256) {
    int i2 = idx >> 5, j = idx & 31;
    h2 p;
    p.x = (_Float16)Wg1[i2 * 64 + j];
    p.y = (_Float16)Wg1[i2 * 64 + 32 + j];
    Wp[idx] = __builtin_bit_cast(unsigned int, p);
  }

  // ---- phase A: stage c1/c2/c3 for this wave's 32 edges ----
  int e32 = lane & 31;
  int sv = src[ebase + e32];                   // coalesced vector loads
  int dv = dst[ebase + e32];
  float bc1v = bc1[lane];
  float bc2v = bc2[lane & 31];
  // c3 pre-activation per-lane (lanes 0..31 = edges)
  float p3s = P3[sv] + P3[dv];
  if (lane < 32) wb[e32 * 102 + 96] = (_Float16)p3s;
#pragma unroll
  for (int e = 0; e < 32; ++e) {
    int s = __builtin_amdgcn_readlane(sv, e);  // SGPR, no memory op
    int d = __builtin_amdgcn_readlane(dv, e);
    float c1v = sigf(P1[(size_t)s * 64 + lane] + P1[(size_t)d * 64 + lane] + bc1v);
    wb[e * 102 + lane] = (_Float16)c1v;
    int sd = (lane < 32) ? s : d;
    float c2p = P2[(size_t)sd * 32 + (lane & 31)];
    float c2sum = c2p + __shfl_xor(c2p, 32);
    if (lane < 32) wb[e * 102 + 64 + lane] = (_Float16)sigf(c2sum + bc2v);
  }
  __syncthreads();

  // ---- phase B: lane = edge + 32*half; halves split K ----
  int e = lane & 31, h = lane >> 5;
  const _Float16* myrow = wb + e * 102;
  const unsigned int* myrow32 = (const unsigned int*)myrow;
  float a[32];
  if (h == 0) {
#pragma unroll
    for (int j2 = 0; j2 < 16; ++j2) {
      h2 c2p = __builtin_bit_cast(h2, myrow32[32 + j2]);
      a[2*j2]   = bg1[2*j2]   + (float)c2p.x;
      a[2*j2+1] = bg1[2*j2+1] + (float)c2p.y;
    }
  } else {
#pragma unroll
    for (int j = 0; j < 32; ++j) a[j] = 0.f;
  }
#pragma unroll
  for (int i2 = 0; i2 < 16; ++i2) {
    int irow = 16 * h + i2;
    h2 c1p = __builtin_bit_cast(h2, myrow32[irow]);
    const unsigned int* wrow = Wp + irow * 32;
#pragma unroll
    for (int j4 = 0; j4 < 8; ++j4) {
      uint4 wq = ((const uint4*)wrow)[j4];     // uniform-addr LDS read
      a[j4*4+0] = fdot2f(c1p, __builtin_bit_cast(h2, wq.x), a[j4*4+0]);
      a[j4*4+1] = fdot2f(c1p, __builtin_bit_cast(h2, wq.y), a[j4*4+1]);
      a[j4*4+2] = fdot2f(c1p, __builtin_bit_cast(h2, wq.z), a[j4*4+2]);
      a[j4*4+3] = fdot2f(c1p, __builtin_bit_cast(h2, wq.w), a[j4*4+3]);
    }
  }
#pragma unroll
  for (int j = 0; j < 32; ++j) a[j] += __shfl_xor(a[j], 32);
  float oacc = 0.f;
#pragma unroll
  for (int j = 0; j < 32; ++j) oacc += sigf(a[j]) * Wg2[j];
  float c3 = sigf((float)myrow[96] + bc3[0]);
  if (h == 0) out[ebase + e] = sigf(oacc + bg2[0] + c3);
}

extern "C" void kernel_launch(void* const* d_in, const int* in_sizes, int n_in,
                              void* d_out, int out_size, void* d_ws, size_t ws_size,
                              hipStream_t stream)
{
  const float* x   = (const float*)d_in[0];
  const int*   src = (const int*)d_in[1];
  const int*   dst = (const int*)d_in[2];
  const float* Wn1 = (const float*)d_in[3];
  const float* bn1 = (const float*)d_in[4];
  const float* Wc1 = (const float*)d_in[5];
  const float* bc1 = (const float*)d_in[6];
  const float* Wn2 = (const float*)d_in[7];
  const float* bn2 = (const float*)d_in[8];
  const float* Wc2 = (const float*)d_in[9];
  const float* bc2 = (const float*)d_in[10];
  const float* Wn3 = (const float*)d_in[11];
  const float* bn3 = (const float*)d_in[12];
  const float* Wc3 = (const float*)d_in[13];
  const float* bc3 = (const float*)d_in[14];
  const float* Wg1 = (const float*)d_in[15];
  const float* bg1 = (const float*)d_in[16];
  const float* Wg2 = (const float*)d_in[17];
  const float* bg2 = (const float*)d_in[18];
  float* out = (float*)d_out;

  float* ws  = (float*)d_ws;
  float* AGG = ws;                           // N*64 (reused)
  float* Q2  = AGG + (size_t)N_NODES * 64;
  float* P1  = Q2  + (size_t)N_NODES * 64;
  float* Q3  = P1  + (size_t)N_NODES * 64;
  float* P2  = Q3  + (size_t)N_NODES * 32;
  float* P3  = P2  + (size_t)N_NODES * 32;
  int* rowptr = (int*)(P3 + N_NODES);
  int* cursor = rowptr + (N_NODES + 1);
  int* col    = cursor + N_NODES;

  // ---- build CSR by dst ----
  hipMemsetAsync(cursor, 0, (size_t)N_NODES * sizeof(int), stream);
  hist_kernel<<<N_EDGES / 256, 256, 0, stream>>>(dst, cursor);
  scan_kernel<<<1, 1024, 0, stream>>>(cursor, rowptr, cursor);
  fill_kernel<<<N_EDGES / 256, 256, 0, stream>>>(src, dst, cursor, col);

  // layer 1
  gather_agg<64><<<(N_NODES + 3) / 4, 256, 0, stream>>>(x, rowptr, col, AGG);
  node1_kernel<<<(N_NODES + 63) / 64, 256, 0, stream>>>(x, AGG, Wn1, bn1, Wn2, Wc1, Q2, P1);
  // layer 2
  gather_agg<64><<<(N_NODES + 3) / 4, 256, 0, stream>>>(Q2, rowptr, col, AGG);
  node2_kernel<<<(N_NODES + 255) / 256, 256, 0, stream>>>(Q2, AGG, bn2, Wn3, Wc2, Q3, P2);
  // layer 3
  gather_agg<32><<<(N_NODES + 3) / 4, 256, 0, stream>>>(Q3, rowptr, col, AGG);
  node3_kernel<<<(N_NODES + 255) / 256, 256, 0, stream>>>(Q3, AGG, bn3, Wc3, P3);
  // edge-level epilogue
  edge_kernel<<<N_EDGES / 128, 256, 0, stream>>>(src, dst, P1, P2, P3,
      bc1, bc2, bc3, Wg1, bg1, Wg2, bg2, out);
}

// Round 4
// 498.305 us; speedup vs baseline: 4.7395x; 1.0040x over previous
//
#include <hip/hip_runtime.h>

#define N_NODES 50000
#define N_EDGES 800000

typedef _Float16 h2 __attribute__((ext_vector_type(2)));

__device__ __forceinline__ float sigf(float v) {
  return __builtin_amdgcn_rcpf(1.0f + __expf(-v));
}
__device__ __forceinline__ float fdot2f(h2 a, h2 b, float c) {
#if __has_builtin(__builtin_amdgcn_fdot2)
  return __builtin_amdgcn_fdot2(a, b, c, false);
#else
  return c + (float)a.x * (float)b.x + (float)a.y * (float)b.y;
#endif
}
__device__ __forceinline__ unsigned packh2(float a, float b) {
  h2 p; p.x = (_Float16)a; p.y = (_Float16)b;
  return __builtin_bit_cast(unsigned, p);
}
__device__ __forceinline__ float2 unpackh2(unsigned u) {
  h2 p = __builtin_bit_cast(h2, u);
  return make_float2((float)p.x, (float)p.y);
}

// ---- convert x (f32 [N,64]) -> x16 (f16-pair uints [N,32]) ----
__global__ __launch_bounds__(256) void cvt16_kernel(
    const float* __restrict__ x, unsigned* __restrict__ x16)
{
  int i = blockIdx.x * 256 + threadIdx.x;   // uint index, N*32 total
  if (i >= N_NODES * 32) return;
  float2 v = ((const float2*)x)[i];
  x16[i] = packh2(v.x, v.y);
}

// ---- CSR build ----
__global__ __launch_bounds__(256) void hist_kernel(
    const int* __restrict__ dst, int* __restrict__ cnt)
{
  int e = blockIdx.x * 256 + threadIdx.x;
  if (e < N_EDGES) atomicAdd(&cnt[dst[e]], 1);
}

__global__ __launch_bounds__(1024) void scan_kernel(
    const int* __restrict__ cnt, int* __restrict__ rowptr,
    int* __restrict__ cursor)
{
  __shared__ int wsum[16];
  int tid = threadIdx.x, lane = tid & 63, w = tid >> 6;
  int carry = 0;
  if (tid == 0) rowptr[0] = 0;
  for (int base = 0; base < N_NODES; base += 1024) {
    int i = base + tid;
    int v = (i < N_NODES) ? cnt[i] : 0;
    int x = v;
#pragma unroll
    for (int off = 1; off < 64; off <<= 1) {
      int y = __shfl_up(x, off);
      if (lane >= off) x += y;
    }
    if (lane == 63) wsum[w] = x;
    __syncthreads();
    if (w == 0 && lane < 16) {
      int s = wsum[lane];
#pragma unroll
      for (int off = 1; off < 16; off <<= 1) {
        int y = __shfl_up(s, off);
        if (lane >= off) s += y;
      }
      wsum[lane] = s;
    }
    __syncthreads();
    int woff = (w == 0) ? 0 : wsum[w - 1];
    int incl = x + woff + carry;
    if (i < N_NODES) {
      rowptr[i + 1] = incl;
      cursor[i] = incl - v;
    }
    carry += wsum[15];
    __syncthreads();
  }
}

__global__ __launch_bounds__(256) void fill_kernel(
    const int* __restrict__ src, const int* __restrict__ dst,
    int* __restrict__ cursor, int* __restrict__ col)
{
  int e = blockIdx.x * 256 + threadIdx.x;
  if (e >= N_EDGES) return;
  int pos = atomicAdd(&cursor[dst[e]], 1);
  col[pos] = src[e];
}

// ---- gather aggregation from f16 tables; agg written f32 ----
template<int D>
__global__ __launch_bounds__(256) void gather_agg16(
    const unsigned* __restrict__ feat16, const int* __restrict__ rowptr,
    const int* __restrict__ col, float* __restrict__ agg)
{
  int w = threadIdx.x >> 6;
  int lane = threadIdx.x & 63;
  int n = blockIdx.x * 4 + w;
  if (n >= N_NODES) return;
  int beg = rowptr[n], end = rowptr[n + 1];
  if (D == 64) {
    int h = lane >> 5, c = lane & 31;   // halves take even/odd edges
    float ax = 0.f, ay = 0.f;
    for (int k0 = beg; k0 < end; k0 += 64) {
      int kk = k0 + lane;
      int cv = (kk < end) ? col[kk] : 0;
      int m = end - k0; if (m > 64) m = 64;
      int e = 0;
      for (; e + 1 < m; e += 2) {
        int s0 = __builtin_amdgcn_readlane(cv, e);
        int s1 = __builtin_amdgcn_readlane(cv, e + 1);
        int sd = h ? s1 : s0;
        float2 p = unpackh2(feat16[(size_t)sd * 32 + c]);
        ax += p.x; ay += p.y;
      }
      if (e < m && h == 0) {
        int s0 = __builtin_amdgcn_readlane(cv, e);
        float2 p = unpackh2(feat16[(size_t)s0 * 32 + c]);
        ax += p.x; ay += p.y;
      }
    }
    ax += __shfl_xor(ax, 32); ay += __shfl_xor(ay, 32);
    if (h == 0) *(float2*)&agg[(size_t)n * 64 + 2 * c] = make_float2(ax, ay);
  } else {  // D == 32: quarters take 4 consecutive edges
    int q = lane >> 4, c = lane & 15;
    float ax = 0.f, ay = 0.f;
    for (int k0 = beg; k0 < end; k0 += 64) {
      int kk = k0 + lane;
      int cv = (kk < end) ? col[kk] : 0;
      int m = end - k0; if (m > 64) m = 64;
      int e = 0;
      for (; e + 3 < m; e += 4) {
        int s0 = __builtin_amdgcn_readlane(cv, e);
        int s1 = __builtin_amdgcn_readlane(cv, e + 1);
        int s2 = __builtin_amdgcn_readlane(cv, e + 2);
        int s3 = __builtin_amdgcn_readlane(cv, e + 3);
        int se = (q == 0) ? s0 : (q == 1) ? s1 : (q == 2) ? s2 : s3;
        float2 p = unpackh2(feat16[(size_t)se * 16 + c]);
        ax += p.x; ay += p.y;
      }
      int r = m - e;
      if (r > 0) {
        int s0 = __builtin_amdgcn_readlane(cv, e);
        int s1 = (r > 1) ? __builtin_amdgcn_readlane(cv, e + 1) : 0;
        int s2 = (r > 2) ? __builtin_amdgcn_readlane(cv, e + 2) : 0;
        int se = (q == 1) ? s1 : (q == 2) ? s2 : s0;
        if (q < r) {
          float2 p = unpackh2(feat16[(size_t)se * 16 + c]);
          ax += p.x; ay += p.y;
        }
      }
    }
    ax += __shfl_xor(ax, 32); ay += __shfl_xor(ay, 32);
    ax += __shfl_xor(ax, 16); ay += __shfl_xor(ay, 16);
    if (q == 0) *(float2*)&agg[(size_t)n * 32 + 2 * c] = make_float2(ax, ay);
  }
}

// ---- node layer 1: t = x + agg; h1 = sig(t@Wn1+bn1); Q2_16 = h1@Wn2; P1_16 = h1@Wc1 ----
__global__ __launch_bounds__(256) void node1_kernel(
    const float* __restrict__ x, const float* __restrict__ agg,
    const float* __restrict__ Wn1, const float* __restrict__ bn1,
    const float* __restrict__ Wn2, const float* __restrict__ Wc1,
    unsigned* __restrict__ Q2_16, unsigned* __restrict__ P1_16)
{
  __shared__ __align__(16) float h1buf[64 * 132];
  int lane = threadIdx.x & 63;
  int w = __builtin_amdgcn_readfirstlane(threadIdx.x >> 6);
  int node = blockIdx.x * 64 + lane;
  int nc = node < N_NODES ? node : N_NODES - 1;
  const float4* xr = (const float4*)(x + (size_t)nc * 64);
  const float4* gr = (const float4*)(agg + (size_t)nc * 64);
  float t[64];
#pragma unroll
  for (int i4 = 0; i4 < 16; ++i4) {
    float4 xv = xr[i4], gv = gr[i4];
    t[i4*4+0] = xv.x + gv.x; t[i4*4+1] = xv.y + gv.y;
    t[i4*4+2] = xv.z + gv.z; t[i4*4+3] = xv.w + gv.w;
  }
  int jb = w * 32;
  float a[32];
#pragma unroll
  for (int j = 0; j < 32; ++j) a[j] = bn1[jb + j];
#pragma unroll
  for (int i = 0; i < 64; ++i) {
    float ti = t[i];
    const float* wr = Wn1 + i * 128 + jb;
#pragma unroll
    for (int j = 0; j < 32; ++j) a[j] += ti * wr[j];
  }
#pragma unroll
  for (int j4 = 0; j4 < 8; ++j4) {
    float4 hv;
    hv.x = sigf(a[j4*4+0]); hv.y = sigf(a[j4*4+1]);
    hv.z = sigf(a[j4*4+2]); hv.w = sigf(a[j4*4+3]);
    *(float4*)&h1buf[lane * 132 + jb + j4 * 4] = hv;
  }
  __syncthreads();
  int cb = w * 16;
  float q[16], p[16];
#pragma unroll
  for (int j = 0; j < 16; ++j) { q[j] = 0.f; p[j] = 0.f; }
#pragma unroll 4
  for (int i4 = 0; i4 < 32; ++i4) {
    float4 h = *(const float4*)&h1buf[lane * 132 + i4 * 4];
    float hv[4] = {h.x, h.y, h.z, h.w};
#pragma unroll
    for (int k = 0; k < 4; ++k) {
      const float* w2 = Wn2 + (i4 * 4 + k) * 64 + cb;
      const float* wc = Wc1 + (i4 * 4 + k) * 64 + cb;
      float hk = hv[k];
#pragma unroll
      for (int j = 0; j < 16; ++j) { q[j] += hk * w2[j]; p[j] += hk * wc[j]; }
    }
  }
  if (node < N_NODES) {
    unsigned qp[8], pp[8];
#pragma unroll
    for (int j2 = 0; j2 < 8; ++j2) {
      qp[j2] = packh2(q[2*j2], q[2*j2+1]);
      pp[j2] = packh2(p[2*j2], p[2*j2+1]);
    }
    unsigned* qo = Q2_16 + (size_t)node * 32 + w * 8;
    unsigned* po = P1_16 + (size_t)node * 32 + w * 8;
    ((uint4*)qo)[0] = make_uint4(qp[0], qp[1], qp[2], qp[3]);
    ((uint4*)qo)[1] = make_uint4(qp[4], qp[5], qp[6], qp[7]);
    ((uint4*)po)[0] = make_uint4(pp[0], pp[1], pp[2], pp[3]);
    ((uint4*)po)[1] = make_uint4(pp[4], pp[5], pp[6], pp[7]);
  }
}

// ---- node layer 2: h2 = sig(Q2+agg+bn2); Q3_16 = h2@Wn3; P2_16 = h2@Wc2 ----
__global__ __launch_bounds__(256) void node2_kernel(
    const unsigned* __restrict__ Q2_16, const float* __restrict__ agg,
    const float* __restrict__ bn2, const float* __restrict__ Wn3,
    const float* __restrict__ Wc2, unsigned* __restrict__ Q3_16,
    unsigned* __restrict__ P2_16)
{
  int n = blockIdx.x * 256 + threadIdx.x;
  if (n >= N_NODES) return;
  const uint4* qr = (const uint4*)(Q2_16 + (size_t)n * 32);
  const float4* gr = (const float4*)(agg + (size_t)n * 64);
  float h[64];
#pragma unroll
  for (int i8 = 0; i8 < 8; ++i8) {
    uint4 v = qr[i8];
    float4 g0 = gr[2*i8], g1 = gr[2*i8+1];
    float2 a0 = unpackh2(v.x), a1 = unpackh2(v.y);
    float2 a2 = unpackh2(v.z), a3 = unpackh2(v.w);
    int b = i8 * 8;
    h[b+0] = sigf(a0.x + g0.x + bn2[b+0]);
    h[b+1] = sigf(a0.y + g0.y + bn2[b+1]);
    h[b+2] = sigf(a1.x + g0.z + bn2[b+2]);
    h[b+3] = sigf(a1.y + g0.w + bn2[b+3]);
    h[b+4] = sigf(a2.x + g1.x + bn2[b+4]);
    h[b+5] = sigf(a2.y + g1.y + bn2[b+5]);
    h[b+6] = sigf(a3.x + g1.z + bn2[b+6]);
    h[b+7] = sigf(a3.y + g1.w + bn2[b+7]);
  }
  float a[32];
#pragma unroll
  for (int j = 0; j < 32; ++j) a[j] = 0.f;
#pragma unroll
  for (int i = 0; i < 64; ++i) {
    float hi = h[i];
    const float* wr = Wn3 + i * 32;
#pragma unroll
    for (int j = 0; j < 32; ++j) a[j] += hi * wr[j];
  }
  {
    unsigned* qo = Q3_16 + (size_t)n * 16;
#pragma unroll
    for (int j8 = 0; j8 < 4; ++j8)
      ((uint4*)qo)[j8] = make_uint4(packh2(a[8*j8], a[8*j8+1]), packh2(a[8*j8+2], a[8*j8+3]),
                                    packh2(a[8*j8+4], a[8*j8+5]), packh2(a[8*j8+6], a[8*j8+7]));
  }
#pragma unroll
  for (int j = 0; j < 32; ++j) a[j] = 0.f;
#pragma unroll
  for (int i = 0; i < 64; ++i) {
    float hi = h[i];
    const float* wr = Wc2 + i * 32;
#pragma unroll
    for (int j = 0; j < 32; ++j) a[j] += hi * wr[j];
  }
  {
    unsigned* po = P2_16 + (size_t)n * 16;
#pragma unroll
    for (int j8 = 0; j8 < 4; ++j8)
      ((uint4*)po)[j8] = make_uint4(packh2(a[8*j8], a[8*j8+1]), packh2(a[8*j8+2], a[8*j8+3]),
                                    packh2(a[8*j8+4], a[8*j8+5]), packh2(a[8*j8+6], a[8*j8+7]));
  }
}

// ---- node layer 3: h3 = sig(Q3+agg+bn3); P3_16 = h3@Wc3 ----
__global__ __launch_bounds__(256) void node3_kernel(
    const unsigned* __restrict__ Q3_16, const float* __restrict__ agg,
    const float* __restrict__ bn3, const float* __restrict__ Wc3,
    _Float16* __restrict__ P3_16)
{
  int n = blockIdx.x * 256 + threadIdx.x;
  if (n >= N_NODES) return;
  const uint4* qr = (const uint4*)(Q3_16 + (size_t)n * 16);
  const float4* gr = (const float4*)(agg + (size_t)n * 32);
  float acc = 0.f;
#pragma unroll
  for (int i4 = 0; i4 < 4; ++i4) {
    uint4 v = qr[i4];
    float4 g0 = gr[2*i4], g1 = gr[2*i4+1];
    float2 a0 = unpackh2(v.x), a1 = unpackh2(v.y);
    float2 a2 = unpackh2(v.z), a3 = unpackh2(v.w);
    int b = i4 * 8;
    acc += sigf(a0.x + g0.x + bn3[b+0]) * Wc3[b+0];
    acc += sigf(a0.y + g0.y + bn3[b+1]) * Wc3[b+1];
    acc += sigf(a1.x + g0.z + bn3[b+2]) * Wc3[b+2];
    acc += sigf(a1.y + g0.w + bn3[b+3]) * Wc3[b+3];
    acc += sigf(a2.x + g1.x + bn3[b+4]) * Wc3[b+4];
    acc += sigf(a2.y + g1.y + bn3[b+5]) * Wc3[b+5];
    acc += sigf(a3.x + g1.z + bn3[b+6]) * Wc3[b+6];
    acc += sigf(a3.y + g1.w + bn3[b+7]) * Wc3[b+7];
  }
  P3_16[n] = (_Float16)acc;
}

// ---- edge kernel: f16 table gathers, f16 LDS staging, v_dot2 GEMM ----
__global__ __launch_bounds__(256, 4) void edge_kernel(
    const int* __restrict__ src, const int* __restrict__ dst,
    const unsigned* __restrict__ P1_16, const unsigned* __restrict__ P2_16,
    const _Float16* __restrict__ P3_16,
    const float* __restrict__ bc1, const float* __restrict__ bc2,
    const float* __restrict__ bc3,
    const float* __restrict__ Wg1, const float* __restrict__ bg1,
    const float* __restrict__ Wg2, const float* __restrict__ bg2,
    float* __restrict__ out)
{
  __shared__ unsigned int Wp[1024];            // f16-pair packed Wg1
  __shared__ _Float16 sbuf[128 * 102];         // per-edge rows: c1[64] c2[32] c3

  int lane = threadIdx.x & 63;
  int w = threadIdx.x >> 6;
  int ebase = blockIdx.x * 128 + w * 32;
  _Float16* wb = sbuf + w * 32 * 102;

  for (int idx = threadIdx.x; idx < 1024; idx += 256) {
    int i2 = idx >> 5, j = idx & 31;
    Wp[idx] = packh2(Wg1[i2 * 64 + j], Wg1[i2 * 64 + 32 + j]);
  }

  // ---- phase A ----
  int e32 = lane & 31;
  int sv = src[ebase + e32];
  int dv = dst[ebase + e32];
  // c3 (lanes 0..31)
  if (lane < 32)
    wb[e32 * 102 + 96] = (_Float16)((float)P3_16[sv] + (float)P3_16[dv]);

  // c1: 32 edges; lane<32 reads s-row pair-col, lane>=32 reads d-row
  {
    int hh = lane >> 5, c = lane & 31;
    float b1a = bc1[2*c], b1b = bc1[2*c+1];
#pragma unroll
    for (int e = 0; e < 32; ++e) {
      int s = __builtin_amdgcn_readlane(sv, e);
      int d = __builtin_amdgcn_readlane(dv, e);
      int row = hh ? d : s;
      float2 p = unpackh2(P1_16[(size_t)row * 32 + c]);
      float fx = p.x + __shfl_xor(p.x, 32);
      float fy = p.y + __shfl_xor(p.y, 32);
      if (hh == 0)
        ((unsigned*)(wb + e * 102))[c] = packh2(sigf(fx + b1a), sigf(fy + b1b));
    }
  }
  // c2: 2 edges per iter; quarters = {s0,d0,s1,d1}
  {
    int q = lane >> 4, cc = lane & 15;
    float b2a = bc2[2*cc], b2b = bc2[2*cc+1];
#pragma unroll
    for (int eo = 0; eo < 16; ++eo) {
      int e0 = 2 * eo, e1 = 2 * eo + 1;
      int s0 = __builtin_amdgcn_readlane(sv, e0);
      int d0 = __builtin_amdgcn_readlane(dv, e0);
      int s1 = __builtin_amdgcn_readlane(sv, e1);
      int d1 = __builtin_amdgcn_readlane(dv, e1);
      int row = (q == 0) ? s0 : (q == 1) ? d0 : (q == 2) ? s1 : d1;
      float2 p = unpackh2(P2_16[(size_t)row * 16 + cc]);
      float fx = p.x + __shfl_xor(p.x, 16);
      float fy = p.y + __shfl_xor(p.y, 16);
      if ((q & 1) == 0) {
        int e = (q == 0) ? e0 : e1;
        ((unsigned*)(wb + e * 102 + 64))[cc] = packh2(sigf(fx + b2a), sigf(fy + b2b));
      }
    }
  }
  __syncthreads();

  // ---- phase B: lane = edge + 32*half; halves split K ----
  int e = lane & 31, h = lane >> 5;
  const _Float16* myrow = wb + e * 102;
  const unsigned int* myrow32 = (const unsigned int*)myrow;
  float a[32];
  if (h == 0) {
#pragma unroll
    for (int j2 = 0; j2 < 16; ++j2) {
      float2 c2p = unpackh2(myrow32[32 + j2]);
      a[2*j2]   = bg1[2*j2]   + c2p.x;
      a[2*j2+1] = bg1[2*j2+1] + c2p.y;
    }
  } else {
#pragma unroll
    for (int j = 0; j < 32; ++j) a[j] = 0.f;
  }
#pragma unroll
  for (int i2 = 0; i2 < 16; ++i2) {
    int irow = 16 * h + i2;
    h2 c1p = __builtin_bit_cast(h2, myrow32[irow]);
    const unsigned int* wrow = Wp + irow * 32;
#pragma unroll
    for (int j4 = 0; j4 < 8; ++j4) {
      uint4 wq = ((const uint4*)wrow)[j4];
      a[j4*4+0] = fdot2f(c1p, __builtin_bit_cast(h2, wq.x), a[j4*4+0]);
      a[j4*4+1] = fdot2f(c1p, __builtin_bit_cast(h2, wq.y), a[j4*4+1]);
      a[j4*4+2] = fdot2f(c1p, __builtin_bit_cast(h2, wq.z), a[j4*4+2]);
      a[j4*4+3] = fdot2f(c1p, __builtin_bit_cast(h2, wq.w), a[j4*4+3]);
    }
  }
#pragma unroll
  for (int j = 0; j < 32; ++j) a[j] += __shfl_xor(a[j], 32);
  float oacc = 0.f;
#pragma unroll
  for (int j = 0; j < 32; ++j) oacc += sigf(a[j]) * Wg2[j];
  float c3 = sigf((float)myrow[96] + bc3[0]);
  if (h == 0) out[ebase + e] = sigf(oacc + bg2[0] + c3);
}

extern "C" void kernel_launch(void* const* d_in, const int* in_sizes, int n_in,
                              void* d_out, int out_size, void* d_ws, size_t ws_size,
                              hipStream_t stream)
{
  const float* x   = (const float*)d_in[0];
  const int*   src = (const int*)d_in[1];
  const int*   dst = (const int*)d_in[2];
  const float* Wn1 = (const float*)d_in[3];
  const float* bn1 = (const float*)d_in[4];
  const float* Wc1 = (const float*)d_in[5];
  const float* bc1 = (const float*)d_in[6];
  const float* Wn2 = (const float*)d_in[7];
  const float* bn2 = (const float*)d_in[8];
  const float* Wc2 = (const float*)d_in[9];
  const float* bc2 = (const float*)d_in[10];
  const float* Wn3 = (const float*)d_in[11];
  const float* bn3 = (const float*)d_in[12];
  const float* Wc3 = (const float*)d_in[13];
  const float* bc3 = (const float*)d_in[14];
  const float* Wg1 = (const float*)d_in[15];
  const float* bg1 = (const float*)d_in[16];
  const float* Wg2 = (const float*)d_in[17];
  const float* bg2 = (const float*)d_in[18];
  float* out = (float*)d_out;

  char* base = (char*)d_ws;
  float*    AGG   = (float*)base;                       base += (size_t)N_NODES * 64 * 4;
  unsigned* X16   = (unsigned*)base;                    base += (size_t)N_NODES * 32 * 4;
  unsigned* Q2_16 = (unsigned*)base;                    base += (size_t)N_NODES * 32 * 4;
  unsigned* P1_16 = (unsigned*)base;                    base += (size_t)N_NODES * 32 * 4;
  unsigned* Q3_16 = (unsigned*)base;                    base += (size_t)N_NODES * 16 * 4;
  unsigned* P2_16 = (unsigned*)base;                    base += (size_t)N_NODES * 16 * 4;
  _Float16* P3_16 = (_Float16*)base;                    base += ((size_t)N_NODES * 2 + 14) / 16 * 16;
  int* rowptr = (int*)base;                             base += (size_t)(N_NODES + 1) * 4;
  int* cursor = (int*)base;                             base += (size_t)N_NODES * 4;
  int* col    = (int*)base;

  // x -> f16 table; CSR build
  cvt16_kernel<<<(N_NODES * 32 + 255) / 256, 256, 0, stream>>>(x, X16);
  hipMemsetAsync(cursor, 0, (size_t)N_NODES * sizeof(int), stream);
  hist_kernel<<<N_EDGES / 256, 256, 0, stream>>>(dst, cursor);
  scan_kernel<<<1, 1024, 0, stream>>>(cursor, rowptr, cursor);
  fill_kernel<<<N_EDGES / 256, 256, 0, stream>>>(src, dst, cursor, col);

  // layer 1
  gather_agg16<64><<<(N_NODES + 3) / 4, 256, 0, stream>>>(X16, rowptr, col, AGG);
  node1_kernel<<<(N_NODES + 63) / 64, 256, 0, stream>>>(x, AGG, Wn1, bn1, Wn2, Wc1, Q2_16, P1_16);
  // layer 2
  gather_agg16<64><<<(N_NODES + 3) / 4, 256, 0, stream>>>(Q2_16, rowptr, col, AGG);
  node2_kernel<<<(N_NODES + 255) / 256, 256, 0, stream>>>(Q2_16, AGG, bn2, Wn3, Wc2, Q3_16, P2_16);
  // layer 3
  gather_agg16<32><<<(N_NODES + 3) / 4, 256, 0, stream>>>(Q3_16, rowptr, col, AGG);
  node3_kernel<<<(N_NODES + 255) / 256, 256, 0, stream>>>(Q3_16, AGG, bn3, Wc3, P3_16);
  // edge-level epilogue
  edge_kernel<<<N_EDGES / 128, 256, 0, stream>>>(src, dst, P1_16, P2_16, P3_16,
      bc1, bc2, bc3, Wg1, bg1, Wg2, bg2, out);
}

// Round 5
// 361.937 us; speedup vs baseline: 6.5252x; 1.3768x over previous
//
#include <hip/hip_runtime.h>

#define N_NODES 50000
#define N_EDGES 800000
#define NBLK_SCAN ((N_NODES + 255) / 256)   // 196
#define CVT_B 6250                          // N_NODES*32/256
#define HIST_B 3125                         // N_EDGES/256

typedef _Float16 h2 __attribute__((ext_vector_type(2)));
typedef _Float16 f16x8 __attribute__((ext_vector_type(8)));
typedef float f32x4 __attribute__((ext_vector_type(4)));

__device__ __forceinline__ float sigf(float v) {
  return __builtin_amdgcn_rcpf(1.0f + __expf(-v));
}
__device__ __forceinline__ unsigned packh2(float a, float b) {
  return __builtin_bit_cast(unsigned, __builtin_amdgcn_cvt_pkrtz(a, b));
}
__device__ __forceinline__ h2 packh2v(float a, float b) {
  return __builtin_bit_cast(h2, __builtin_amdgcn_cvt_pkrtz(a, b));
}
__device__ __forceinline__ float2 unpackh2(unsigned u) {
  h2 p = __builtin_bit_cast(h2, u);
  return make_float2((float)p.x, (float)p.y);
}

// ---- prep: x->f16 table | dst histogram | Wg1 -> MFMA B-fragment layout ----
__global__ __launch_bounds__(256) void prep_kernel(
    const float* __restrict__ x, unsigned* __restrict__ x16,
    const int* __restrict__ dst, int* __restrict__ cnt,
    const float* __restrict__ Wg1, uint4* __restrict__ Bfrag)
{
  int b = blockIdx.x;
  if (b < CVT_B) {
    int i = b * 256 + threadIdx.x;
    float2 v = ((const float2*)x)[i];
    x16[i] = packh2(v.x, v.y);
  } else if (b < CVT_B + HIST_B) {
    int e = (b - CVT_B) * 256 + threadIdx.x;
    atomicAdd(&cnt[dst[e]], 1);
  } else {
    int t = threadIdx.x;
    if (t < 64) {
      int n0 = t & 15, chunk = t >> 4;
#pragma unroll
      for (int ks = 0; ks < 2; ++ks)
#pragma unroll
        for (int nh = 0; nh < 2; ++nh) {
          f16x8 vv;
#pragma unroll
          for (int i = 0; i < 8; ++i) {
            int k = ks * 32 + chunk * 8 + i;
            int n = nh * 16 + n0;
            vv[i] = (_Float16)Wg1[k * 32 + n];
          }
          Bfrag[(ks * 2 + nh) * 64 + t] = __builtin_bit_cast(uint4, vv);
        }
    }
  }
}

// ---- parallel scan: block sums -> scan of sums -> final scan ----
__global__ __launch_bounds__(256) void scan1_kernel(
    const int* __restrict__ cnt, int* __restrict__ bsum)
{
  int i = blockIdx.x * 256 + threadIdx.x;
  int v = (i < N_NODES) ? cnt[i] : 0;
#pragma unroll
  for (int off = 32; off; off >>= 1) v += __shfl_xor(v, off);
  __shared__ int ws[4];
  if ((threadIdx.x & 63) == 0) ws[threadIdx.x >> 6] = v;
  __syncthreads();
  if (threadIdx.x == 0) bsum[blockIdx.x] = ws[0] + ws[1] + ws[2] + ws[3];
}

__global__ __launch_bounds__(256) void scan2_kernel(int* __restrict__ bsum)
{
  int tid = threadIdx.x, lane = tid & 63, w = tid >> 6;
  int v = (tid < NBLK_SCAN) ? bsum[tid] : 0;
  int x = v;
#pragma unroll
  for (int off = 1; off < 64; off <<= 1) {
    int y = __shfl_up(x, off);
    if (lane >= off) x += y;
  }
  __shared__ int ws[4];
  if (lane == 63) ws[w] = x;
  __syncthreads();
  int woff = 0;
#pragma unroll
  for (int k = 0; k < 4; ++k) if (k < w) woff += ws[k];
  if (tid < NBLK_SCAN) bsum[tid] = x + woff - v;   // exclusive
}

__global__ __launch_bounds__(256) void scan3_kernel(
    const int* __restrict__ cnt, const int* __restrict__ bsum,
    int* __restrict__ rowptr, int* __restrict__ cursor)
{
  int i = blockIdx.x * 256 + threadIdx.x;
  int lane = threadIdx.x & 63, w = threadIdx.x >> 6;
  int v = (i < N_NODES) ? cnt[i] : 0;
  int x = v;
#pragma unroll
  for (int off = 1; off < 64; off <<= 1) {
    int y = __shfl_up(x, off);
    if (lane >= off) x += y;
  }
  __shared__ int ws[4];
  if (lane == 63) ws[w] = x;
  __syncthreads();
  int woff = bsum[blockIdx.x];
#pragma unroll
  for (int k = 0; k < 4; ++k) if (k < w) woff += ws[k];
  if (i < N_NODES) {
    int excl = woff + x - v;
    cursor[i] = excl;
    rowptr[i + 1] = excl + v;
    if (i == 0) rowptr[0] = 0;
  }
}

__global__ __launch_bounds__(256) void fill_kernel(
    const int* __restrict__ src, const int* __restrict__ dst,
    int* __restrict__ cursor, int* __restrict__ col)
{
  int e = blockIdx.x * 256 + threadIdx.x;
  if (e >= N_EDGES) return;
  int pos = atomicAdd(&cursor[dst[e]], 1);
  col[pos] = src[e];
}

// ---- gather aggregation from f16 tables; agg written f32 ----
template<int D>
__global__ __launch_bounds__(256) void gather_agg16(
    const unsigned* __restrict__ feat16, const int* __restrict__ rowptr,
    const int* __restrict__ col, float* __restrict__ agg)
{
  int w = threadIdx.x >> 6;
  int lane = threadIdx.x & 63;
  int n = blockIdx.x * 4 + w;
  if (n >= N_NODES) return;
  int beg = rowptr[n], end = rowptr[n + 1];
  if (D == 64) {
    int h = lane >> 5, c = lane & 31;
    float ax = 0.f, ay = 0.f;
    for (int k0 = beg; k0 < end; k0 += 64) {
      int kk = k0 + lane;
      int cv = (kk < end) ? col[kk] : 0;
      int m = end - k0; if (m > 64) m = 64;
      int e = 0;
#pragma unroll 2
      for (; e + 1 < m; e += 2) {
        int s0 = __builtin_amdgcn_readlane(cv, e);
        int s1 = __builtin_amdgcn_readlane(cv, e + 1);
        int sd = h ? s1 : s0;
        float2 p = unpackh2(feat16[(size_t)sd * 32 + c]);
        ax += p.x; ay += p.y;
      }
      if (e < m && h == 0) {
        int s0 = __builtin_amdgcn_readlane(cv, e);
        float2 p = unpackh2(feat16[(size_t)s0 * 32 + c]);
        ax += p.x; ay += p.y;
      }
    }
    ax += __shfl_xor(ax, 32); ay += __shfl_xor(ay, 32);
    if (h == 0) *(float2*)&agg[(size_t)n * 64 + 2 * c] = make_float2(ax, ay);
  } else {
    int q = lane >> 4, c = lane & 15;
    float ax = 0.f, ay = 0.f;
    for (int k0 = beg; k0 < end; k0 += 64) {
      int kk = k0 + lane;
      int cv = (kk < end) ? col[kk] : 0;
      int m = end - k0; if (m > 64) m = 64;
      int e = 0;
#pragma unroll 2
      for (; e + 3 < m; e += 4) {
        int s0 = __builtin_amdgcn_readlane(cv, e);
        int s1 = __builtin_amdgcn_readlane(cv, e + 1);
        int s2 = __builtin_amdgcn_readlane(cv, e + 2);
        int s3 = __builtin_amdgcn_readlane(cv, e + 3);
        int se = (q == 0) ? s0 : (q == 1) ? s1 : (q == 2) ? s2 : s3;
        float2 p = unpackh2(feat16[(size_t)se * 16 + c]);
        ax += p.x; ay += p.y;
      }
      int r = m - e;
      if (r > 0) {
        int s0 = __builtin_amdgcn_readlane(cv, e);
        int s1 = (r > 1) ? __builtin_amdgcn_readlane(cv, e + 1) : 0;
        int s2 = (r > 2) ? __builtin_amdgcn_readlane(cv, e + 2) : 0;
        int se = (q == 1) ? s1 : (q == 2) ? s2 : s0;
        if (q < r) {
          float2 p = unpackh2(feat16[(size_t)se * 16 + c]);
          ax += p.x; ay += p.y;
        }
      }
    }
    ax += __shfl_xor(ax, 32); ay += __shfl_xor(ay, 32);
    ax += __shfl_xor(ax, 16); ay += __shfl_xor(ay, 16);
    if (q == 0) *(float2*)&agg[(size_t)n * 32 + 2 * c] = make_float2(ax, ay);
  }
}

// ---- node layer 1 ----
__global__ __launch_bounds__(256) void node1_kernel(
    const float* __restrict__ x, const float* __restrict__ agg,
    const float* __restrict__ Wn1, const float* __restrict__ bn1,
    const float* __restrict__ Wn2, const float* __restrict__ Wc1,
    unsigned* __restrict__ Q2_16, unsigned* __restrict__ P1_16)
{
  __shared__ __align__(16) float h1buf[64 * 132];
  int lane = threadIdx.x & 63;
  int w = __builtin_amdgcn_readfirstlane(threadIdx.x >> 6);
  int node = blockIdx.x * 64 + lane;
  int nc = node < N_NODES ? node : N_NODES - 1;
  const float4* xr = (const float4*)(x + (size_t)nc * 64);
  const float4* gr = (const float4*)(agg + (size_t)nc * 64);
  float t[64];
#pragma unroll
  for (int i4 = 0; i4 < 16; ++i4) {
    float4 xv = xr[i4], gv = gr[i4];
    t[i4*4+0] = xv.x + gv.x; t[i4*4+1] = xv.y + gv.y;
    t[i4*4+2] = xv.z + gv.z; t[i4*4+3] = xv.w + gv.w;
  }
  int jb = w * 32;
  float a[32];
#pragma unroll
  for (int j = 0; j < 32; ++j) a[j] = bn1[jb + j];
#pragma unroll
  for (int i = 0; i < 64; ++i) {
    float ti = t[i];
    const float* wr = Wn1 + i * 128 + jb;
#pragma unroll
    for (int j = 0; j < 32; ++j) a[j] += ti * wr[j];
  }
#pragma unroll
  for (int j4 = 0; j4 < 8; ++j4) {
    float4 hv;
    hv.x = sigf(a[j4*4+0]); hv.y = sigf(a[j4*4+1]);
    hv.z = sigf(a[j4*4+2]); hv.w = sigf(a[j4*4+3]);
    *(float4*)&h1buf[lane * 132 + jb + j4 * 4] = hv;
  }
  __syncthreads();
  int cb = w * 16;
  float q[16], p[16];
#pragma unroll
  for (int j = 0; j < 16; ++j) { q[j] = 0.f; p[j] = 0.f; }
#pragma unroll 4
  for (int i4 = 0; i4 < 32; ++i4) {
    float4 h = *(const float4*)&h1buf[lane * 132 + i4 * 4];
    float hv[4] = {h.x, h.y, h.z, h.w};
#pragma unroll
    for (int k = 0; k < 4; ++k) {
      const float* w2 = Wn2 + (i4 * 4 + k) * 64 + cb;
      const float* wc = Wc1 + (i4 * 4 + k) * 64 + cb;
      float hk = hv[k];
#pragma unroll
      for (int j = 0; j < 16; ++j) { q[j] += hk * w2[j]; p[j] += hk * wc[j]; }
    }
  }
  if (node < N_NODES) {
    unsigned qp[8], pp[8];
#pragma unroll
    for (int j2 = 0; j2 < 8; ++j2) {
      qp[j2] = packh2(q[2*j2], q[2*j2+1]);
      pp[j2] = packh2(p[2*j2], p[2*j2+1]);
    }
    unsigned* qo = Q2_16 + (size_t)node * 32 + w * 8;
    unsigned* po = P1_16 + (size_t)node * 32 + w * 8;
    ((uint4*)qo)[0] = make_uint4(qp[0], qp[1], qp[2], qp[3]);
    ((uint4*)qo)[1] = make_uint4(qp[4], qp[5], qp[6], qp[7]);
    ((uint4*)po)[0] = make_uint4(pp[0], pp[1], pp[2], pp[3]);
    ((uint4*)po)[1] = make_uint4(pp[4], pp[5], pp[6], pp[7]);
  }
}

// ---- node layer 2 ----
__global__ __launch_bounds__(256) void node2_kernel(
    const unsigned* __restrict__ Q2_16, const float* __restrict__ agg,
    const float* __restrict__ bn2, const float* __restrict__ Wn3,
    const float* __restrict__ Wc2, unsigned* __restrict__ Q3_16,
    unsigned* __restrict__ P2_16)
{
  int n = blockIdx.x * 256 + threadIdx.x;
  if (n >= N_NODES) return;
  const uint4* qr = (const uint4*)(Q2_16 + (size_t)n * 32);
  const float4* gr = (const float4*)(agg + (size_t)n * 64);
  float h[64];
#pragma unroll
  for (int i8 = 0; i8 < 8; ++i8) {
    uint4 v = qr[i8];
    float4 g0 = gr[2*i8], g1 = gr[2*i8+1];
    float2 a0 = unpackh2(v.x), a1 = unpackh2(v.y);
    float2 a2 = unpackh2(v.z), a3 = unpackh2(v.w);
    int b = i8 * 8;
    h[b+0] = sigf(a0.x + g0.x + bn2[b+0]);
    h[b+1] = sigf(a0.y + g0.y + bn2[b+1]);
    h[b+2] = sigf(a1.x + g0.z + bn2[b+2]);
    h[b+3] = sigf(a1.y + g0.w + bn2[b+3]);
    h[b+4] = sigf(a2.x + g1.x + bn2[b+4]);
    h[b+5] = sigf(a2.y + g1.y + bn2[b+5]);
    h[b+6] = sigf(a3.x + g1.z + bn2[b+6]);
    h[b+7] = sigf(a3.y + g1.w + bn2[b+7]);
  }
  float a[32];
#pragma unroll
  for (int j = 0; j < 32; ++j) a[j] = 0.f;
#pragma unroll
  for (int i = 0; i < 64; ++i) {
    float hi = h[i];
    const float* wr = Wn3 + i * 32;
#pragma unroll
    for (int j = 0; j < 32; ++j) a[j] += hi * wr[j];
  }
  {
    unsigned* qo = Q3_16 + (size_t)n * 16;
#pragma unroll
    for (int j8 = 0; j8 < 4; ++j8)
      ((uint4*)qo)[j8] = make_uint4(packh2(a[8*j8], a[8*j8+1]), packh2(a[8*j8+2], a[8*j8+3]),
                                    packh2(a[8*j8+4], a[8*j8+5]), packh2(a[8*j8+6], a[8*j8+7]));
  }
#pragma unroll
  for (int j = 0; j < 32; ++j) a[j] = 0.f;
#pragma unroll
  for (int i = 0; i < 64; ++i) {
    float hi = h[i];
    const float* wr = Wc2 + i * 32;
#pragma unroll
    for (int j = 0; j < 32; ++j) a[j] += hi * wr[j];
  }
  {
    unsigned* po = P2_16 + (size_t)n * 16;
#pragma unroll
    for (int j8 = 0; j8 < 4; ++j8)
      ((uint4*)po)[j8] = make_uint4(packh2(a[8*j8], a[8*j8+1]), packh2(a[8*j8+2], a[8*j8+3]),
                                    packh2(a[8*j8+4], a[8*j8+5]), packh2(a[8*j8+6], a[8*j8+7]));
  }
}

// ---- node layer 3 ----
__global__ __launch_bounds__(256) void node3_kernel(
    const unsigned* __restrict__ Q3_16, const float* __restrict__ agg,
    const float* __restrict__ bn3, const float* __restrict__ Wc3,
    _Float16* __restrict__ P3_16)
{
  int n = blockIdx.x * 256 + threadIdx.x;
  if (n >= N_NODES) return;
  const uint4* qr = (const uint4*)(Q3_16 + (size_t)n * 16);
  const float4* gr = (const float4*)(agg + (size_t)n * 32);
  float acc = 0.f;
#pragma unroll
  for (int i4 = 0; i4 < 4; ++i4) {
    uint4 v = qr[i4];
    float4 g0 = gr[2*i4], g1 = gr[2*i4+1];
    float2 a0 = unpackh2(v.x), a1 = unpackh2(v.y);
    float2 a2 = unpackh2(v.z), a3 = unpackh2(v.w);
    int b = i4 * 8;
    acc += sigf(a0.x + g0.x + bn3[b+0]) * Wc3[b+0];
    acc += sigf(a0.y + g0.y + bn3[b+1]) * Wc3[b+1];
    acc += sigf(a1.x + g0.z + bn3[b+2]) * Wc3[b+2];
    acc += sigf(a1.y + g0.w + bn3[b+3]) * Wc3[b+3];
    acc += sigf(a2.x + g1.x + bn3[b+4]) * Wc3[b+4];
    acc += sigf(a2.y + g1.y + bn3[b+5]) * Wc3[b+5];
    acc += sigf(a3.x + g1.z + bn3[b+6]) * Wc3[b+6];
    acc += sigf(a3.y + g1.w + bn3[b+7]) * Wc3[b+7];
  }
  P3_16[n] = (_Float16)acc;
}

// ---- edge kernel: shuffle-free f16 staging + MFMA GEMV ----
// wave = 32 edges; stride 104 f16 per edge row: c1[64] c2[32] c3 @96
__global__ __launch_bounds__(256) void edge_kernel(
    const int* __restrict__ src, const int* __restrict__ dst,
    const unsigned* __restrict__ P1_16, const unsigned* __restrict__ P2_16,
    const _Float16* __restrict__ P3_16, const uint4* __restrict__ Bfrag,
    const float* __restrict__ bc1, const float* __restrict__ bc2,
    const float* __restrict__ bc3, const float* __restrict__ bg1,
    const float* __restrict__ Wg2, const float* __restrict__ bg2,
    float* __restrict__ out)
{
  __shared__ __align__(16) _Float16 sbuf[4][32 * 104];
  __shared__ int eidx[4][64];
  int lane = threadIdx.x & 63;
  int w = threadIdx.x >> 6;
  int ebase = blockIdx.x * 128 + w * 32;
  _Float16* wb = &sbuf[w][0];

  // stage indices: lanes 0..31 = src, 32..63 = dst
  int e32 = lane & 31;
  const int* bp = (lane < 32) ? src : dst;
  int myi = bp[ebase + e32];
  eidx[w][lane] = myi;

  // B-fragments (preloaded, coalesced)
  f16x8 Bf[2][2];
#pragma unroll
  for (int ks = 0; ks < 2; ++ks)
#pragma unroll
    for (int nh = 0; nh < 2; ++nh)
      Bf[ks][nh] = __builtin_bit_cast(f16x8, Bfrag[(ks * 2 + nh) * 64 + lane]);

  // c3: P3[s]+P3[d]
  {
    float p3v = (float)P3_16[myi];
    float pair = __shfl_xor(p3v, 32);
    if (lane < 32) wb[e32 * 104 + 96] = (_Float16)(p3v + pair);
  }

  // c1: 2 edges / iteration, no cross-lane ops
  {
    int c = lane & 31, half = lane >> 5;
    float b1a = bc1[2 * c], b1b = bc1[2 * c + 1];
#pragma unroll
    for (int it = 0; it < 16; ++it) {
      int e = 2 * it + half;
      int s = eidx[w][e];
      int d = eidx[w][32 + e];
      h2 ps = *(const h2*)(P1_16 + (size_t)s * 32 + c);
      h2 pd = *(const h2*)(P1_16 + (size_t)d * 32 + c);
      h2 sum = ps + pd;
      float fx = (float)sum.x + b1a, fy = (float)sum.y + b1b;
      *(h2*)(wb + e * 104 + 2 * c) = packh2v(sigf(fx), sigf(fy));
    }
  }
  // c2: 4 edges / iteration
  {
    int cc = lane & 15, eq = lane >> 4;
    float b2a = bc2[2 * cc], b2b = bc2[2 * cc + 1];
#pragma unroll
    for (int it = 0; it < 8; ++it) {
      int e = 4 * it + eq;
      int s = eidx[w][e];
      int d = eidx[w][32 + e];
      h2 ps = *(const h2*)(P2_16 + (size_t)s * 16 + cc);
      h2 pd = *(const h2*)(P2_16 + (size_t)d * 16 + cc);
      h2 sum = ps + pd;
      float fx = (float)sum.x + b2a, fy = (float)sum.y + b2b;
      *(h2*)(wb + e * 104 + 64 + 2 * cc) = packh2v(sigf(fx), sigf(fy));
    }
  }
  // no barrier: each wave consumes only its own staged rows (lgkm ordering within wave)

  // ---- phase B: MFMA. 2 groups of 16 edges; A: row=lane&15, k=8*(lane>>4)+i ----
  int row = lane & 15, chunk = lane >> 4;
  float bg1v0 = bg1[row], bg1v1 = bg1[16 + row];
  float wg2v0 = Wg2[row], wg2v1 = Wg2[16 + row];
  float bg2v = bg2[0], bc3v = bc3[0];
#pragma unroll
  for (int g = 0; g < 2; ++g) {
    const _Float16* abase = wb + (16 * g + row) * 104 + chunk * 8;
    f16x8 A0 = *(const f16x8*)abase;          // k 0..31
    f16x8 A1 = *(const f16x8*)(abase + 32);   // k 32..63
    f32x4 acc0 = {0.f, 0.f, 0.f, 0.f}, acc1 = {0.f, 0.f, 0.f, 0.f};
    acc0 = __builtin_amdgcn_mfma_f32_16x16x32_f16(A0, Bf[0][0], acc0, 0, 0, 0);
    acc1 = __builtin_amdgcn_mfma_f32_16x16x32_f16(A0, Bf[0][1], acc1, 0, 0, 0);
    acc0 = __builtin_amdgcn_mfma_f32_16x16x32_f16(A1, Bf[1][0], acc0, 0, 0, 0);
    acc1 = __builtin_amdgcn_mfma_f32_16x16x32_f16(A1, Bf[1][1], acc1, 0, 0, 0);
#pragma unroll
    for (int r = 0; r < 4; ++r) {
      int e = 16 * g + chunk * 4 + r;         // C layout: row=(lane>>4)*4+reg
      float c2a = (float)wb[e * 104 + 64 + row];
      float c2b = (float)wb[e * 104 + 80 + row];
      float v0 = sigf(acc0[r] + bg1v0 + c2a) * wg2v0;
      float v1 = sigf(acc1[r] + bg1v1 + c2b) * wg2v1;
      float part = v0 + v1;
      part += __shfl_xor(part, 1);
      part += __shfl_xor(part, 2);
      part += __shfl_xor(part, 4);
      part += __shfl_xor(part, 8);
      float c3v = (float)wb[e * 104 + 96];
      if (row == 0)
        out[ebase + e] = sigf(part + bg2v + sigf(c3v + bc3v));
    }
  }
}

extern "C" void kernel_launch(void* const* d_in, const int* in_sizes, int n_in,
                              void* d_out, int out_size, void* d_ws, size_t ws_size,
                              hipStream_t stream)
{
  const float* x   = (const float*)d_in[0];
  const int*   src = (const int*)d_in[1];
  const int*   dst = (const int*)d_in[2];
  const float* Wn1 = (const float*)d_in[3];
  const float* bn1 = (const float*)d_in[4];
  const float* Wc1 = (const float*)d_in[5];
  const float* bc1 = (const float*)d_in[6];
  const float* Wn2 = (const float*)d_in[7];
  const float* bn2 = (const float*)d_in[8];
  const float* Wc2 = (const float*)d_in[9];
  const float* bc2 = (const float*)d_in[10];
  const float* Wn3 = (const float*)d_in[11];
  const float* bn3 = (const float*)d_in[12];
  const float* Wc3 = (const float*)d_in[13];
  const float* bc3 = (const float*)d_in[14];
  const float* Wg1 = (const float*)d_in[15];
  const float* bg1 = (const float*)d_in[16];
  const float* Wg2 = (const float*)d_in[17];
  const float* bg2 = (const float*)d_in[18];
  float* out = (float*)d_out;

  char* base = (char*)d_ws;
  float*    AGG   = (float*)base;    base += (size_t)N_NODES * 64 * 4;
  unsigned* X16   = (unsigned*)base; base += (size_t)N_NODES * 32 * 4;
  unsigned* Q2_16 = (unsigned*)base; base += (size_t)N_NODES * 32 * 4;
  unsigned* P1_16 = (unsigned*)base; base += (size_t)N_NODES * 32 * 4;
  unsigned* Q3_16 = (unsigned*)base; base += (size_t)N_NODES * 16 * 4;
  unsigned* P2_16 = (unsigned*)base; base += (size_t)N_NODES * 16 * 4;
  _Float16* P3_16 = (_Float16*)base; base += ((size_t)N_NODES * 2 + 15) / 16 * 16;
  int* rowptr = (int*)base;          base += (size_t)(N_NODES + 1) * 4;
  int* cursor = (int*)base;          base += (size_t)N_NODES * 4;
  int* col    = (int*)base;          base += (size_t)N_EDGES * 4;
  int* bsum   = (int*)base;          base += (size_t)NBLK_SCAN * 4;
  uint4* Bfrag = (uint4*)base;       base += 4 * 64 * 16;

  // prep (cvt + hist + Bfrag) and CSR build
  hipMemsetAsync(cursor, 0, (size_t)N_NODES * sizeof(int), stream);
  prep_kernel<<<CVT_B + HIST_B + 1, 256, 0, stream>>>(x, X16, dst, cursor, Wg1, Bfrag);
  scan1_kernel<<<NBLK_SCAN, 256, 0, stream>>>(cursor, bsum);
  scan2_kernel<<<1, 256, 0, stream>>>(bsum);
  scan3_kernel<<<NBLK_SCAN, 256, 0, stream>>>(cursor, bsum, rowptr, cursor);
  fill_kernel<<<HIST_B, 256, 0, stream>>>(src, dst, cursor, col);

  // layer 1
  gather_agg16<64><<<(N_NODES + 3) / 4, 256, 0, stream>>>(X16, rowptr, col, AGG);
  node1_kernel<<<(N_NODES + 63) / 64, 256, 0, stream>>>(x, AGG, Wn1, bn1, Wn2, Wc1, Q2_16, P1_16);
  // layer 2
  gather_agg16<64><<<(N_NODES + 3) / 4, 256, 0, stream>>>(Q2_16, rowptr, col, AGG);
  node2_kernel<<<(N_NODES + 255) / 256, 256, 0, stream>>>(Q2_16, AGG, bn2, Wn3, Wc2, Q3_16, P2_16);
  // layer 3
  gather_agg16<32><<<(N_NODES + 3) / 4, 256, 0, stream>>>(Q3_16, rowptr, col, AGG);
  node3_kernel<<<(N_NODES + 255) / 256, 256, 0, stream>>>(Q3_16, AGG, bn3, Wc3, P3_16);
  // edge-level epilogue
  edge_kernel<<<N_EDGES / 128, 256, 0, stream>>>(src, dst, P1_16, P2_16, P3_16, Bfrag,
      bc1, bc2, bc3, bg1, Wg2, bg2, out);
}

// Round 6
// 253.103 us; speedup vs baseline: 9.3310x; 1.4300x over previous
//
#include <hip/hip_runtime.h>

#define N_NODES 50000
#define N_EDGES 800000
#define NBLK_SCAN ((N_NODES + 255) / 256)   // 196
#define CVT_B 6250                          // N_NODES*32/256
#define HIST_B 3125                         // N_EDGES/256
#define NODE_B ((N_NODES + 63) / 64)        // 782

typedef _Float16 h2 __attribute__((ext_vector_type(2)));
typedef _Float16 f16x8 __attribute__((ext_vector_type(8)));
typedef float f32x4 __attribute__((ext_vector_type(4)));

__device__ __forceinline__ float sigf(float v) {
  return __builtin_amdgcn_rcpf(1.0f + __expf(-v));
}
__device__ __forceinline__ unsigned packh2(float a, float b) {
  return __builtin_bit_cast(unsigned, __builtin_amdgcn_cvt_pkrtz(a, b));
}
__device__ __forceinline__ h2 packh2v(float a, float b) {
  return __builtin_bit_cast(h2, __builtin_amdgcn_cvt_pkrtz(a, b));
}
__device__ __forceinline__ float2 unpackh2(unsigned u) {
  h2 p = __builtin_bit_cast(h2, u);
  return make_float2((float)p.x, (float)p.y);
}
__device__ __forceinline__ unsigned addpk(unsigned a, unsigned b) {
  h2 r = __builtin_bit_cast(h2, a) + __builtin_bit_cast(h2, b);
  return __builtin_bit_cast(unsigned, r);
}
#define MFMA16(A, B, C) __builtin_amdgcn_mfma_f32_16x16x32_f16(A, __builtin_bit_cast(f16x8, B), C, 0, 0, 0)

// ---- prep: x->f16 | dst histogram | all weight matrices -> MFMA B-frag layout ----
__global__ __launch_bounds__(256) void prep_kernel(
    const float* __restrict__ x, unsigned* __restrict__ x16,
    const int* __restrict__ dst, int* __restrict__ cnt,
    const float* __restrict__ Wn1, const float* __restrict__ Wn2,
    const float* __restrict__ Wc1, const float* __restrict__ Wn3,
    const float* __restrict__ Wc2, const float* __restrict__ Wg1,
    uint4* __restrict__ Wn1f, uint4* __restrict__ Wn2f, uint4* __restrict__ Wc1f,
    uint4* __restrict__ Wn3f, uint4* __restrict__ Wc2f, uint4* __restrict__ Wg1f)
{
  int b = blockIdx.x;
  if (b < CVT_B) {
    int i = b * 256 + threadIdx.x;
    float2 v = ((const float2*)x)[i];
    x16[i] = packh2(v.x, v.y);
  } else if (b < CVT_B + HIST_B) {
    int e = (b - CVT_B) * 256 + threadIdx.x;
    atomicAdd(&cnt[dst[e]], 1);
  } else {
    int lane = threadIdx.x & 63, w = threadIdx.x >> 6;
    int n15 = lane & 15, chunk = lane >> 4;
    if (w == 0) {           // Wn1f: K=64, N=128 -> 8 nt x 2 ks
#pragma unroll
      for (int f = 0; f < 16; ++f) {
        int nt = f >> 1, ks = f & 1;
        int n = nt * 16 + n15;
        f16x8 vv;
#pragma unroll
        for (int i = 0; i < 8; ++i) vv[i] = (_Float16)Wn1[(ks * 32 + chunk * 8 + i) * 128 + n];
        Wn1f[f * 64 + lane] = __builtin_bit_cast(uint4, vv);
      }
    } else if (w == 1) {    // Wn2f: K=128, N=64 -> 4 nt x 4 ks
#pragma unroll
      for (int f = 0; f < 16; ++f) {
        int nt = f >> 2, ks = f & 3;
        int n = nt * 16 + n15;
        f16x8 vv;
#pragma unroll
        for (int i = 0; i < 8; ++i) vv[i] = (_Float16)Wn2[(ks * 32 + chunk * 8 + i) * 64 + n];
        Wn2f[f * 64 + lane] = __builtin_bit_cast(uint4, vv);
      }
    } else if (w == 2) {    // Wc1f: K=128, N=64 -> 4 nt x 4 ks
#pragma unroll
      for (int f = 0; f < 16; ++f) {
        int nt = f >> 2, ks = f & 3;
        int n = nt * 16 + n15;
        f16x8 vv;
#pragma unroll
        for (int i = 0; i < 8; ++i) vv[i] = (_Float16)Wc1[(ks * 32 + chunk * 8 + i) * 64 + n];
        Wc1f[f * 64 + lane] = __builtin_bit_cast(uint4, vv);
      }
    } else {                // Wn3f, Wc2f: K=64,N=32 -> 2 nt x 2 ks; Wg1f legacy layout
#pragma unroll
      for (int f = 0; f < 4; ++f) {
        int nt = f >> 1, ks = f & 1;
        int n = nt * 16 + n15;
        f16x8 v3, vc;
#pragma unroll
        for (int i = 0; i < 8; ++i) {
          int k = ks * 32 + chunk * 8 + i;
          v3[i] = (_Float16)Wn3[k * 32 + n];
          vc[i] = (_Float16)Wc2[k * 32 + n];
        }
        Wn3f[f * 64 + lane] = __builtin_bit_cast(uint4, v3);
        Wc2f[f * 64 + lane] = __builtin_bit_cast(uint4, vc);
      }
#pragma unroll
      for (int ks = 0; ks < 2; ++ks)
#pragma unroll
        for (int nh = 0; nh < 2; ++nh) {
          f16x8 vv;
#pragma unroll
          for (int i = 0; i < 8; ++i)
            vv[i] = (_Float16)Wg1[(ks * 32 + chunk * 8 + i) * 32 + nh * 16 + n15];
          Wg1f[(ks * 2 + nh) * 64 + lane] = __builtin_bit_cast(uint4, vv);
        }
    }
  }
}

// ---- parallel scan ----
__global__ __launch_bounds__(256) void scan1_kernel(
    const int* __restrict__ cnt, int* __restrict__ bsum)
{
  int i = blockIdx.x * 256 + threadIdx.x;
  int v = (i < N_NODES) ? cnt[i] : 0;
#pragma unroll
  for (int off = 32; off; off >>= 1) v += __shfl_xor(v, off);
  __shared__ int ws[4];
  if ((threadIdx.x & 63) == 0) ws[threadIdx.x >> 6] = v;
  __syncthreads();
  if (threadIdx.x == 0) bsum[blockIdx.x] = ws[0] + ws[1] + ws[2] + ws[3];
}

__global__ __launch_bounds__(256) void scan2_kernel(int* __restrict__ bsum)
{
  int tid = threadIdx.x, lane = tid & 63, w = tid >> 6;
  int v = (tid < NBLK_SCAN) ? bsum[tid] : 0;
  int x = v;
#pragma unroll
  for (int off = 1; off < 64; off <<= 1) {
    int y = __shfl_up(x, off);
    if (lane >= off) x += y;
  }
  __shared__ int ws[4];
  if (lane == 63) ws[w] = x;
  __syncthreads();
  int woff = 0;
#pragma unroll
  for (int k = 0; k < 4; ++k) if (k < w) woff += ws[k];
  if (tid < NBLK_SCAN) bsum[tid] = x + woff - v;
}

__global__ __launch_bounds__(256) void scan3_kernel(
    const int* __restrict__ cnt, const int* __restrict__ bsum,
    int* __restrict__ rowptr, int* __restrict__ cursor)
{
  int i = blockIdx.x * 256 + threadIdx.x;
  int lane = threadIdx.x & 63, w = threadIdx.x >> 6;
  int v = (i < N_NODES) ? cnt[i] : 0;
  int x = v;
#pragma unroll
  for (int off = 1; off < 64; off <<= 1) {
    int y = __shfl_up(x, off);
    if (lane >= off) x += y;
  }
  __shared__ int ws[4];
  if (lane == 63) ws[w] = x;
  __syncthreads();
  int woff = bsum[blockIdx.x];
#pragma unroll
  for (int k = 0; k < 4; ++k) if (k < w) woff += ws[k];
  if (i < N_NODES) {
    int excl = woff + x - v;
    cursor[i] = excl;
    rowptr[i + 1] = excl + v;
    if (i == 0) rowptr[0] = 0;
  }
}

__global__ __launch_bounds__(256) void fill_kernel(
    const int* __restrict__ src, const int* __restrict__ dst,
    int* __restrict__ cursor, int* __restrict__ col)
{
  int e = blockIdx.x * 256 + threadIdx.x;
  if (e >= N_EDGES) return;
  int pos = atomicAdd(&cursor[dst[e]], 1);
  col[pos] = src[e];
}

// ---- gather aggregation: f16 tables in, packed f16 agg out ----
template<int D>
__global__ __launch_bounds__(256) void gather_agg16(
    const unsigned* __restrict__ feat16, const int* __restrict__ rowptr,
    const int* __restrict__ col, unsigned* __restrict__ agg)
{
  int w = threadIdx.x >> 6;
  int lane = threadIdx.x & 63;
  int n = blockIdx.x * 4 + w;
  if (n >= N_NODES) return;
  int beg = rowptr[n], end = rowptr[n + 1];
  if (D == 64) {
    int h = lane >> 5, c = lane & 31;
    float ax = 0.f, ay = 0.f;
    for (int k0 = beg; k0 < end; k0 += 64) {
      int kk = k0 + lane;
      int cv = (kk < end) ? col[kk] : 0;
      int m = end - k0; if (m > 64) m = 64;
      int e = 0;
#pragma unroll 2
      for (; e + 1 < m; e += 2) {
        int s0 = __builtin_amdgcn_readlane(cv, e);
        int s1 = __builtin_amdgcn_readlane(cv, e + 1);
        int sd = h ? s1 : s0;
        float2 p = unpackh2(feat16[(size_t)sd * 32 + c]);
        ax += p.x; ay += p.y;
      }
      if (e < m && h == 0) {
        int s0 = __builtin_amdgcn_readlane(cv, e);
        float2 p = unpackh2(feat16[(size_t)s0 * 32 + c]);
        ax += p.x; ay += p.y;
      }
    }
    ax += __shfl_xor(ax, 32); ay += __shfl_xor(ay, 32);
    if (h == 0) agg[(size_t)n * 32 + c] = packh2(ax, ay);
  } else {
    int q = lane >> 4, c = lane & 15;
    float ax = 0.f, ay = 0.f;
    for (int k0 = beg; k0 < end; k0 += 64) {
      int kk = k0 + lane;
      int cv = (kk < end) ? col[kk] : 0;
      int m = end - k0; if (m > 64) m = 64;
      int e = 0;
#pragma unroll 2
      for (; e + 3 < m; e += 4) {
        int s0 = __builtin_amdgcn_readlane(cv, e);
        int s1 = __builtin_amdgcn_readlane(cv, e + 1);
        int s2 = __builtin_amdgcn_readlane(cv, e + 2);
        int s3 = __builtin_amdgcn_readlane(cv, e + 3);
        int se = (q == 0) ? s0 : (q == 1) ? s1 : (q == 2) ? s2 : s3;
        float2 p = unpackh2(feat16[(size_t)se * 16 + c]);
        ax += p.x; ay += p.y;
      }
      int r = m - e;
      if (r > 0) {
        int s0 = __builtin_amdgcn_readlane(cv, e);
        int s1 = (r > 1) ? __builtin_amdgcn_readlane(cv, e + 1) : 0;
        int s2 = (r > 2) ? __builtin_amdgcn_readlane(cv, e + 2) : 0;
        int se = (q == 1) ? s1 : (q == 2) ? s2 : s0;
        if (q < r) {
          float2 p = unpackh2(feat16[(size_t)se * 16 + c]);
          ax += p.x; ay += p.y;
        }
      }
    }
    ax += __shfl_xor(ax, 32); ay += __shfl_xor(ay, 32);
    ax += __shfl_xor(ax, 16); ay += __shfl_xor(ay, 16);
    if (q == 0) agg[(size_t)n * 16 + c] = packh2(ax, ay);
  }
}

// ---- node layer 1 (MFMA): t=x+agg (f16 LDS) -> h1 (LDS) -> Q2,P1 (f16) ----
__global__ __launch_bounds__(256) void node1_kernel(
    const unsigned* __restrict__ X16, const unsigned* __restrict__ AGG16,
    const uint4* __restrict__ Wn1f, const uint4* __restrict__ Wn2f,
    const uint4* __restrict__ Wc1f, const float* __restrict__ bn1,
    _Float16* __restrict__ Q2h, _Float16* __restrict__ P1h)
{
  __shared__ __align__(16) _Float16 t_lds[64 * 72];    // 64 k + pad
  __shared__ __align__(16) _Float16 h1_lds[64 * 136];  // 128 k + pad
  int tid = threadIdx.x;
  int lane = tid & 63, w = tid >> 6;
  int nbase = blockIdx.x * 64;

#pragma unroll
  for (int rep = 0; rep < 2; ++rep) {
    int uidx = rep * 1024 + tid * 4;
    int node = uidx >> 5, c = uidx & 31;
    int gn = nbase + node; if (gn > N_NODES - 1) gn = N_NODES - 1;
    uint4 xv = *(const uint4*)(X16 + (size_t)gn * 32 + c);
    uint4 gv = *(const uint4*)(AGG16 + (size_t)gn * 32 + c);
    uint4 tv;
    tv.x = addpk(xv.x, gv.x); tv.y = addpk(xv.y, gv.y);
    tv.z = addpk(xv.z, gv.z); tv.w = addpk(xv.w, gv.w);
    *(uint4*)(t_lds + node * 72 + c * 2) = tv;
  }
  __syncthreads();

  int row16 = lane & 15, chunk = lane >> 4;
  uint4 b1[2][2];
#pragma unroll
  for (int ntl = 0; ntl < 2; ++ntl)
#pragma unroll
    for (int ks = 0; ks < 2; ++ks)
      b1[ntl][ks] = Wn1f[((2 * w + ntl) * 2 + ks) * 64 + lane];

  f32x4 acc[4][2];
#pragma unroll
  for (int mt = 0; mt < 4; ++mt)
#pragma unroll
    for (int ntl = 0; ntl < 2; ++ntl) acc[mt][ntl] = (f32x4){0.f, 0.f, 0.f, 0.f};
#pragma unroll
  for (int mt = 0; mt < 4; ++mt) {
    const _Float16* ab = t_lds + (mt * 16 + row16) * 72 + chunk * 8;
    f16x8 A0 = *(const f16x8*)ab;
    f16x8 A1 = *(const f16x8*)(ab + 32);
#pragma unroll
    for (int ntl = 0; ntl < 2; ++ntl) {
      acc[mt][ntl] = MFMA16(A0, b1[ntl][0], acc[mt][ntl]);
      acc[mt][ntl] = MFMA16(A1, b1[ntl][1], acc[mt][ntl]);
    }
  }
  float bnv0 = bn1[w * 32 + row16], bnv1 = bn1[w * 32 + 16 + row16];
#pragma unroll
  for (int mt = 0; mt < 4; ++mt)
#pragma unroll
    for (int r = 0; r < 4; ++r) {
      int rowl = mt * 16 + chunk * 4 + r;
      h1_lds[rowl * 136 + w * 32 + row16]      = (_Float16)sigf(acc[mt][0][r] + bnv0);
      h1_lds[rowl * 136 + w * 32 + 16 + row16] = (_Float16)sigf(acc[mt][1][r] + bnv1);
    }
  __syncthreads();

  // phase 2: wave w computes Q2 cols [16w,16w+16) and P1 cols [16w,16w+16)
#pragma unroll
  for (int job = 0; job < 2; ++job) {
    const uint4* Wf = job ? Wc1f : Wn2f;
    uint4 bf[4];
#pragma unroll
    for (int ks = 0; ks < 4; ++ks) bf[ks] = Wf[(w * 4 + ks) * 64 + lane];
    f32x4 a2[4];
#pragma unroll
    for (int mt = 0; mt < 4; ++mt) a2[mt] = (f32x4){0.f, 0.f, 0.f, 0.f};
#pragma unroll
    for (int mt = 0; mt < 4; ++mt) {
      const _Float16* hb = h1_lds + (mt * 16 + row16) * 136 + chunk * 8;
#pragma unroll
      for (int ks = 0; ks < 4; ++ks) {
        f16x8 A = *(const f16x8*)(hb + ks * 32);
        a2[mt] = MFMA16(A, bf[ks], a2[mt]);
      }
    }
    _Float16* op = job ? P1h : Q2h;
#pragma unroll
    for (int mt = 0; mt < 4; ++mt)
#pragma unroll
      for (int r = 0; r < 4; ++r) {
        int gn = nbase + mt * 16 + chunk * 4 + r;
        if (gn < N_NODES) op[(size_t)gn * 64 + w * 16 + row16] = (_Float16)a2[mt][r];
      }
  }
}

// ---- node layer 2 (MFMA): h2=sig(Q2+agg+bn2) (f16 LDS) -> Q3,P2 (f16) ----
__global__ __launch_bounds__(256) void node2_kernel(
    const unsigned* __restrict__ Q2u, const unsigned* __restrict__ AGG16,
    const uint4* __restrict__ Wn3f, const uint4* __restrict__ Wc2f,
    const float* __restrict__ bn2, _Float16* __restrict__ Q3h,
    _Float16* __restrict__ P2h)
{
  __shared__ __align__(16) _Float16 t_lds[64 * 72];
  int tid = threadIdx.x, lane = tid & 63, w = tid >> 6;
  int nbase = blockIdx.x * 64;
#pragma unroll
  for (int rep = 0; rep < 2; ++rep) {
    int uidx = rep * 1024 + tid * 4;
    int node = uidx >> 5, c = uidx & 31;
    int gn = nbase + node; if (gn > N_NODES - 1) gn = N_NODES - 1;
    uint4 qv = *(const uint4*)(Q2u + (size_t)gn * 32 + c);
    uint4 gv = *(const uint4*)(AGG16 + (size_t)gn * 32 + c);
    unsigned qa[4] = {qv.x, qv.y, qv.z, qv.w};
    unsigned ga[4] = {gv.x, gv.y, gv.z, gv.w};
    unsigned r[4];
#pragma unroll
    for (int jj = 0; jj < 4; ++jj) {
      float2 q2 = unpackh2(qa[jj]), g2 = unpackh2(ga[jj]);
      int colb = 2 * (c + jj);
      r[jj] = packh2(sigf(q2.x + g2.x + bn2[colb]), sigf(q2.y + g2.y + bn2[colb + 1]));
    }
    *(uint4*)(t_lds + node * 72 + c * 2) = make_uint4(r[0], r[1], r[2], r[3]);
  }
  __syncthreads();
  int row16 = lane & 15, chunk = lane >> 4;
  int mat = w >> 1, nt = w & 1;
  const uint4* Wf = mat ? Wc2f : Wn3f;
  uint4 bf0 = Wf[(nt * 2 + 0) * 64 + lane];
  uint4 bf1 = Wf[(nt * 2 + 1) * 64 + lane];
  f32x4 a2[4];
#pragma unroll
  for (int mt = 0; mt < 4; ++mt) a2[mt] = (f32x4){0.f, 0.f, 0.f, 0.f};
#pragma unroll
  for (int mt = 0; mt < 4; ++mt) {
    const _Float16* ab = t_lds + (mt * 16 + row16) * 72 + chunk * 8;
    f16x8 A0 = *(const f16x8*)ab;
    f16x8 A1 = *(const f16x8*)(ab + 32);
    a2[mt] = MFMA16(A0, bf0, a2[mt]);
    a2[mt] = MFMA16(A1, bf1, a2[mt]);
  }
  _Float16* op = mat ? P2h : Q3h;
#pragma unroll
  for (int mt = 0; mt < 4; ++mt)
#pragma unroll
    for (int r = 0; r < 4; ++r) {
      int gn = nbase + mt * 16 + chunk * 4 + r;
      if (gn < N_NODES) op[(size_t)gn * 32 + nt * 16 + row16] = (_Float16)a2[mt][r];
    }
}

// ---- node layer 3 ----
__global__ __launch_bounds__(256) void node3_kernel(
    const unsigned* __restrict__ Q3u, const unsigned* __restrict__ AGG16,
    const float* __restrict__ bn3, const float* __restrict__ Wc3,
    _Float16* __restrict__ P3h)
{
  int n = blockIdx.x * 256 + threadIdx.x;
  if (n >= N_NODES) return;
  const uint4* qr = (const uint4*)(Q3u + (size_t)n * 16);
  const uint4* gr = (const uint4*)(AGG16 + (size_t)n * 16);
  float acc = 0.f;
#pragma unroll
  for (int i4 = 0; i4 < 4; ++i4) {
    uint4 v = qr[i4], g = gr[i4];
    unsigned va[4] = {v.x, v.y, v.z, v.w}, ga[4] = {g.x, g.y, g.z, g.w};
#pragma unroll
    for (int jj = 0; jj < 4; ++jj) {
      float2 a = unpackh2(va[jj]), b = unpackh2(ga[jj]);
      int colb = i4 * 8 + jj * 2;
      acc += sigf(a.x + b.x + bn3[colb]) * Wc3[colb];
      acc += sigf(a.y + b.y + bn3[colb + 1]) * Wc3[colb + 1];
    }
  }
  P3h[n] = (_Float16)acc;
}

// ---- edge kernel: shuffle-free f16 staging + MFMA GEMV (unchanged) ----
__global__ __launch_bounds__(256) void edge_kernel(
    const int* __restrict__ src, const int* __restrict__ dst,
    const unsigned* __restrict__ P1_16, const unsigned* __restrict__ P2_16,
    const _Float16* __restrict__ P3_16, const uint4* __restrict__ Bfrag,
    const float* __restrict__ bc1, const float* __restrict__ bc2,
    const float* __restrict__ bc3, const float* __restrict__ bg1,
    const float* __restrict__ Wg2, const float* __restrict__ bg2,
    float* __restrict__ out)
{
  __shared__ __align__(16) _Float16 sbuf[4][32 * 104];
  __shared__ int eidx[4][64];
  int lane = threadIdx.x & 63;
  int w = threadIdx.x >> 6;
  int ebase = blockIdx.x * 128 + w * 32;
  _Float16* wb = &sbuf[w][0];

  int e32 = lane & 31;
  const int* bp = (lane < 32) ? src : dst;
  int myi = bp[ebase + e32];
  eidx[w][lane] = myi;

  f16x8 Bf[2][2];
#pragma unroll
  for (int ks = 0; ks < 2; ++ks)
#pragma unroll
    for (int nh = 0; nh < 2; ++nh)
      Bf[ks][nh] = __builtin_bit_cast(f16x8, Bfrag[(ks * 2 + nh) * 64 + lane]);

  {
    float p3v = (float)P3_16[myi];
    float pair = __shfl_xor(p3v, 32);
    if (lane < 32) wb[e32 * 104 + 96] = (_Float16)(p3v + pair);
  }
  {
    int c = lane & 31, half = lane >> 5;
    float b1a = bc1[2 * c], b1b = bc1[2 * c + 1];
#pragma unroll
    for (int it = 0; it < 16; ++it) {
      int e = 2 * it + half;
      int s = eidx[w][e];
      int d = eidx[w][32 + e];
      h2 ps = *(const h2*)(P1_16 + (size_t)s * 32 + c);
      h2 pd = *(const h2*)(P1_16 + (size_t)d * 32 + c);
      h2 sum = ps + pd;
      float fx = (float)sum.x + b1a, fy = (float)sum.y + b1b;
      *(h2*)(wb + e * 104 + 2 * c) = packh2v(sigf(fx), sigf(fy));
    }
  }
  {
    int cc = lane & 15, eq = lane >> 4;
    float b2a = bc2[2 * cc], b2b = bc2[2 * cc + 1];
#pragma unroll
    for (int it = 0; it < 8; ++it) {
      int e = 4 * it + eq;
      int s = eidx[w][e];
      int d = eidx[w][32 + e];
      h2 ps = *(const h2*)(P2_16 + (size_t)s * 16 + cc);
      h2 pd = *(const h2*)(P2_16 + (size_t)d * 16 + cc);
      h2 sum = ps + pd;
      float fx = (float)sum.x + b2a, fy = (float)sum.y + b2b;
      *(h2*)(wb + e * 104 + 64 + 2 * cc) = packh2v(sigf(fx), sigf(fy));
    }
  }

  int row = lane & 15, chunk = lane >> 4;
  float bg1v0 = bg1[row], bg1v1 = bg1[16 + row];
  float wg2v0 = Wg2[row], wg2v1 = Wg2[16 + row];
  float bg2v = bg2[0], bc3v = bc3[0];
#pragma unroll
  for (int g = 0; g < 2; ++g) {
    const _Float16* abase = wb + (16 * g + row) * 104 + chunk * 8;
    f16x8 A0 = *(const f16x8*)abase;
    f16x8 A1 = *(const f16x8*)(abase + 32);
    f32x4 acc0 = {0.f, 0.f, 0.f, 0.f}, acc1 = {0.f, 0.f, 0.f, 0.f};
    acc0 = __builtin_amdgcn_mfma_f32_16x16x32_f16(A0, Bf[0][0], acc0, 0, 0, 0);
    acc1 = __builtin_amdgcn_mfma_f32_16x16x32_f16(A0, Bf[0][1], acc1, 0, 0, 0);
    acc0 = __builtin_amdgcn_mfma_f32_16x16x32_f16(A1, Bf[1][0], acc0, 0, 0, 0);
    acc1 = __builtin_amdgcn_mfma_f32_16x16x32_f16(A1, Bf[1][1], acc1, 0, 0, 0);
#pragma unroll
    for (int r = 0; r < 4; ++r) {
      int e = 16 * g + chunk * 4 + r;
      float c2a = (float)wb[e * 104 + 64 + row];
      float c2b = (float)wb[e * 104 + 80 + row];
      float v0 = sigf(acc0[r] + bg1v0 + c2a) * wg2v0;
      float v1 = sigf(acc1[r] + bg1v1 + c2b) * wg2v1;
      float part = v0 + v1;
      part += __shfl_xor(part, 1);
      part += __shfl_xor(part, 2);
      part += __shfl_xor(part, 4);
      part += __shfl_xor(part, 8);
      float c3v = (float)wb[e * 104 + 96];
      if (row == 0)
        out[ebase + e] = sigf(part + bg2v + sigf(c3v + bc3v));
    }
  }
}

extern "C" void kernel_launch(void* const* d_in, const int* in_sizes, int n_in,
                              void* d_out, int out_size, void* d_ws, size_t ws_size,
                              hipStream_t stream)
{
  const float* x   = (const float*)d_in[0];
  const int*   src = (const int*)d_in[1];
  const int*   dst = (const int*)d_in[2];
  const float* Wn1 = (const float*)d_in[3];
  const float* bn1 = (const float*)d_in[4];
  const float* Wc1 = (const float*)d_in[5];
  const float* bc1 = (const float*)d_in[6];
  const float* Wn2 = (const float*)d_in[7];
  const float* bn2 = (const float*)d_in[8];
  const float* Wc2 = (const float*)d_in[9];
  const float* bc2 = (const float*)d_in[10];
  const float* Wn3 = (const float*)d_in[11];
  const float* bn3 = (const float*)d_in[12];
  const float* Wc3 = (const float*)d_in[13];
  const float* bc3 = (const float*)d_in[14];
  const float* Wg1 = (const float*)d_in[15];
  const float* bg1 = (const float*)d_in[16];
  const float* Wg2 = (const float*)d_in[17];
  const float* bg2 = (const float*)d_in[18];
  float* out = (float*)d_out;

  char* base = (char*)d_ws;
  unsigned* AGG16 = (unsigned*)base; base += (size_t)N_NODES * 32 * 4;
  unsigned* X16   = (unsigned*)base; base += (size_t)N_NODES * 32 * 4;
  unsigned* Q2_16 = (unsigned*)base; base += (size_t)N_NODES * 32 * 4;
  unsigned* P1_16 = (unsigned*)base; base += (size_t)N_NODES * 32 * 4;
  unsigned* Q3_16 = (unsigned*)base; base += (size_t)N_NODES * 16 * 4;
  unsigned* P2_16 = (unsigned*)base; base += (size_t)N_NODES * 16 * 4;
  _Float16* P3_16 = (_Float16*)base; base += ((size_t)N_NODES * 2 + 15) / 16 * 16;
  int* rowptr = (int*)base;          base += (size_t)(N_NODES + 1) * 4;
  int* cursor = (int*)base;          base += (size_t)N_NODES * 4;
  int* col    = (int*)base;          base += (size_t)N_EDGES * 4;
  int* bsum   = (int*)base;          base += (size_t)NBLK_SCAN * 4 + 12;
  uint4* Wg1f = (uint4*)base;        base += 4 * 64 * 16;
  uint4* Wn1f = (uint4*)base;        base += 16 * 64 * 16;
  uint4* Wn2f = (uint4*)base;        base += 16 * 64 * 16;
  uint4* Wc1f = (uint4*)base;        base += 16 * 64 * 16;
  uint4* Wn3f = (uint4*)base;        base += 4 * 64 * 16;
  uint4* Wc2f = (uint4*)base;        base += 4 * 64 * 16;

  // prep (cvt + hist + frag-pack) and CSR build
  hipMemsetAsync(cursor, 0, (size_t)N_NODES * sizeof(int), stream);
  prep_kernel<<<CVT_B + HIST_B + 1, 256, 0, stream>>>(x, X16, dst, cursor,
      Wn1, Wn2, Wc1, Wn3, Wc2, Wg1, Wn1f, Wn2f, Wc1f, Wn3f, Wc2f, Wg1f);
  scan1_kernel<<<NBLK_SCAN, 256, 0, stream>>>(cursor, bsum);
  scan2_kernel<<<1, 256, 0, stream>>>(bsum);
  scan3_kernel<<<NBLK_SCAN, 256, 0, stream>>>(cursor, bsum, rowptr, cursor);
  fill_kernel<<<HIST_B, 256, 0, stream>>>(src, dst, cursor, col);

  // layer 1
  gather_agg16<64><<<(N_NODES + 3) / 4, 256, 0, stream>>>(X16, rowptr, col, AGG16);
  node1_kernel<<<NODE_B, 256, 0, stream>>>(X16, AGG16, Wn1f, Wn2f, Wc1f, bn1,
      (_Float16*)Q2_16, (_Float16*)P1_16);
  // layer 2
  gather_agg16<64><<<(N_NODES + 3) / 4, 256, 0, stream>>>(Q2_16, rowptr, col, AGG16);
  node2_kernel<<<NODE_B, 256, 0, stream>>>(Q2_16, AGG16, Wn3f, Wc2f, bn2,
      (_Float16*)Q3_16, (_Float16*)P2_16);
  // layer 3
  gather_agg16<32><<<(N_NODES + 3) / 4, 256, 0, stream>>>(Q3_16, rowptr, col, AGG16);
  node3_kernel<<<(N_NODES + 255) / 256, 256, 0, stream>>>(Q3_16, AGG16, bn3, Wc3, P3_16);
  // edge-level epilogue
  edge_kernel<<<N_EDGES / 128, 256, 0, stream>>>(src, dst, P1_16, P2_16, P3_16, Wg1f,
      bc1, bc2, bc3, bg1, Wg2, bg2, out);
}

// Round 7
// 240.397 us; speedup vs baseline: 9.8242x; 1.0529x over previous
//
#include <hip/hip_runtime.h>

#define N_NODES 50000
#define N_EDGES 800000
#define NBLK_SCAN ((N_NODES + 255) / 256)   // 196
#define CVT_B 6250                          // N_NODES*32/256
#define HIST_B 3125                         // N_EDGES/256
#define NODE_B ((N_NODES + 63) / 64)        // 782

typedef _Float16 h2 __attribute__((ext_vector_type(2)));
typedef _Float16 f16x8 __attribute__((ext_vector_type(8)));
typedef float f32x4 __attribute__((ext_vector_type(4)));

__device__ __forceinline__ float sigf(float v) {
  return __builtin_amdgcn_rcpf(1.0f + __expf(-v));
}
__device__ __forceinline__ unsigned packh2(float a, float b) {
  return __builtin_bit_cast(unsigned, __builtin_amdgcn_cvt_pkrtz(a, b));
}
__device__ __forceinline__ h2 packh2v(float a, float b) {
  return __builtin_bit_cast(h2, __builtin_amdgcn_cvt_pkrtz(a, b));
}
__device__ __forceinline__ float2 unpackh2(unsigned u) {
  h2 p = __builtin_bit_cast(h2, u);
  return make_float2((float)p.x, (float)p.y);
}
__device__ __forceinline__ void acc4(float& a0, float& a1, float& a2, float& a3, uint2 v) {
  float2 p0 = unpackh2(v.x), p1 = unpackh2(v.y);
  a0 += p0.x; a1 += p0.y; a2 += p1.x; a3 += p1.y;
}
#define MFMA16(A, B, C) __builtin_amdgcn_mfma_f32_16x16x32_f16(A, __builtin_bit_cast(f16x8, B), C, 0, 0, 0)

// ---- prep: x->f16 | dst histogram | weight matrices -> MFMA B-frag layout ----
__global__ __launch_bounds__(256) void prep_kernel(
    const float* __restrict__ x, unsigned* __restrict__ x16,
    const int* __restrict__ dst, int* __restrict__ cnt,
    const float* __restrict__ Wn1, const float* __restrict__ Wn2,
    const float* __restrict__ Wc1, const float* __restrict__ Wn3,
    const float* __restrict__ Wc2, const float* __restrict__ Wg1,
    uint4* __restrict__ Wn1f, uint4* __restrict__ Wn2f, uint4* __restrict__ Wc1f,
    uint4* __restrict__ Wn3f, uint4* __restrict__ Wc2f, uint4* __restrict__ Wg1f)
{
  int b = blockIdx.x;
  if (b < CVT_B) {
    int i = b * 256 + threadIdx.x;
    float2 v = ((const float2*)x)[i];
    x16[i] = packh2(v.x, v.y);
  } else if (b < CVT_B + HIST_B) {
    int e = (b - CVT_B) * 256 + threadIdx.x;
    atomicAdd(&cnt[dst[e]], 1);
  } else {
    int lane = threadIdx.x & 63, w = threadIdx.x >> 6;
    int n15 = lane & 15, chunk = lane >> 4;
    if (w == 0) {           // Wn1f: K=64, N=128 -> 8 nt x 2 ks
#pragma unroll
      for (int f = 0; f < 16; ++f) {
        int nt = f >> 1, ks = f & 1;
        int n = nt * 16 + n15;
        f16x8 vv;
#pragma unroll
        for (int i = 0; i < 8; ++i) vv[i] = (_Float16)Wn1[(ks * 32 + chunk * 8 + i) * 128 + n];
        Wn1f[f * 64 + lane] = __builtin_bit_cast(uint4, vv);
      }
    } else if (w == 1) {    // Wn2f: K=128, N=64 -> 4 nt x 4 ks
#pragma unroll
      for (int f = 0; f < 16; ++f) {
        int nt = f >> 2, ks = f & 3;
        int n = nt * 16 + n15;
        f16x8 vv;
#pragma unroll
        for (int i = 0; i < 8; ++i) vv[i] = (_Float16)Wn2[(ks * 32 + chunk * 8 + i) * 64 + n];
        Wn2f[f * 64 + lane] = __builtin_bit_cast(uint4, vv);
      }
    } else if (w == 2) {    // Wc1f: K=128, N=64 -> 4 nt x 4 ks
#pragma unroll
      for (int f = 0; f < 16; ++f) {
        int nt = f >> 2, ks = f & 3;
        int n = nt * 16 + n15;
        f16x8 vv;
#pragma unroll
        for (int i = 0; i < 8; ++i) vv[i] = (_Float16)Wc1[(ks * 32 + chunk * 8 + i) * 64 + n];
        Wc1f[f * 64 + lane] = __builtin_bit_cast(uint4, vv);
      }
    } else {                // Wn3f, Wc2f: K=64,N=32; Wg1f
#pragma unroll
      for (int f = 0; f < 4; ++f) {
        int nt = f >> 1, ks = f & 1;
        int n = nt * 16 + n15;
        f16x8 v3, vc;
#pragma unroll
        for (int i = 0; i < 8; ++i) {
          int k = ks * 32 + chunk * 8 + i;
          v3[i] = (_Float16)Wn3[k * 32 + n];
          vc[i] = (_Float16)Wc2[k * 32 + n];
        }
        Wn3f[f * 64 + lane] = __builtin_bit_cast(uint4, v3);
        Wc2f[f * 64 + lane] = __builtin_bit_cast(uint4, vc);
      }
#pragma unroll
      for (int ks = 0; ks < 2; ++ks)
#pragma unroll
        for (int nh = 0; nh < 2; ++nh) {
          f16x8 vv;
#pragma unroll
          for (int i = 0; i < 8; ++i)
            vv[i] = (_Float16)Wg1[(ks * 32 + chunk * 8 + i) * 32 + nh * 16 + n15];
          Wg1f[(ks * 2 + nh) * 64 + lane] = __builtin_bit_cast(uint4, vv);
        }
    }
  }
}

// ---- parallel scan ----
__global__ __launch_bounds__(256) void scan1_kernel(
    const int* __restrict__ cnt, int* __restrict__ bsum)
{
  int i = blockIdx.x * 256 + threadIdx.x;
  int v = (i < N_NODES) ? cnt[i] : 0;
#pragma unroll
  for (int off = 32; off; off >>= 1) v += __shfl_xor(v, off);
  __shared__ int ws[4];
  if ((threadIdx.x & 63) == 0) ws[threadIdx.x >> 6] = v;
  __syncthreads();
  if (threadIdx.x == 0) bsum[blockIdx.x] = ws[0] + ws[1] + ws[2] + ws[3];
}

__global__ __launch_bounds__(256) void scan2_kernel(int* __restrict__ bsum)
{
  int tid = threadIdx.x, lane = tid & 63, w = tid >> 6;
  int v = (tid < NBLK_SCAN) ? bsum[tid] : 0;
  int x = v;
#pragma unroll
  for (int off = 1; off < 64; off <<= 1) {
    int y = __shfl_up(x, off);
    if (lane >= off) x += y;
  }
  __shared__ int ws[4];
  if (lane == 63) ws[w] = x;
  __syncthreads();
  int woff = 0;
#pragma unroll
  for (int k = 0; k < 4; ++k) if (k < w) woff += ws[k];
  if (tid < NBLK_SCAN) bsum[tid] = x + woff - v;
}

__global__ __launch_bounds__(256) void scan3_kernel(
    const int* __restrict__ cnt, const int* __restrict__ bsum,
    int* __restrict__ rowptr, int* __restrict__ cursor)
{
  int i = blockIdx.x * 256 + threadIdx.x;
  int lane = threadIdx.x & 63, w = threadIdx.x >> 6;
  int v = (i < N_NODES) ? cnt[i] : 0;
  int x = v;
#pragma unroll
  for (int off = 1; off < 64; off <<= 1) {
    int y = __shfl_up(x, off);
    if (lane >= off) x += y;
  }
  __shared__ int ws[4];
  if (lane == 63) ws[w] = x;
  __syncthreads();
  int woff = bsum[blockIdx.x];
#pragma unroll
  for (int k = 0; k < 4; ++k) if (k < w) woff += ws[k];
  if (i < N_NODES) {
    int excl = woff + x - v;
    cursor[i] = excl;
    rowptr[i + 1] = excl + v;
    if (i == 0) rowptr[0] = 0;
  }
}

__global__ __launch_bounds__(256) void fill_kernel(
    const int* __restrict__ src, const int* __restrict__ dst,
    int* __restrict__ cursor, int* __restrict__ col)
{
  int e = blockIdx.x * 256 + threadIdx.x;
  if (e >= N_EDGES) return;
  int pos = atomicAdd(&cursor[dst[e]], 1);
  col[pos] = src[e];
}

// ---- gather1: T16[n] = x16[n] + sum_{incoming} x16[src]; 4 edges/iter ----
__global__ __launch_bounds__(256) void gather1_kernel(
    const unsigned* __restrict__ X16, const int* __restrict__ rowptr,
    const int* __restrict__ col, unsigned* __restrict__ T16)
{
  int w = threadIdx.x >> 6, lane = threadIdx.x & 63;
  int n = blockIdx.x * 4 + w;
  if (n >= N_NODES) return;
  int beg = rowptr[n], end = rowptr[n + 1];
  int q = lane >> 4, c = lane & 15;
  const uint2* feat2 = (const uint2*)X16;
  float a0 = 0.f, a1 = 0.f, a2 = 0.f, a3 = 0.f;
  for (int k0 = beg; k0 < end; k0 += 64) {
    int kk = k0 + lane;
    int cv = (kk < end) ? col[kk] : 0;
    int m = end - k0; if (m > 64) m = 64;
    int e = 0;
#pragma unroll 2
    for (; e + 3 < m; e += 4) {
      int se = __shfl(cv, e + q);
      uint2 v = feat2[(size_t)se * 16 + c];
      acc4(a0, a1, a2, a3, v);
    }
    int r = m - e;
    if (r) {
      int idx = e + q; if (idx >= m) idx = m - 1;
      int se = __shfl(cv, idx);
      uint2 v = feat2[(size_t)se * 16 + c];
      if (q < r) acc4(a0, a1, a2, a3, v);
    }
  }
  a0 += __shfl_xor(a0, 32); a1 += __shfl_xor(a1, 32);
  a2 += __shfl_xor(a2, 32); a3 += __shfl_xor(a3, 32);
  a0 += __shfl_xor(a0, 16); a1 += __shfl_xor(a1, 16);
  a2 += __shfl_xor(a2, 16); a3 += __shfl_xor(a3, 16);
  if (q == 0) {
    uint2 xv = ((const uint2*)X16)[(size_t)n * 16 + c];
    float2 x0 = unpackh2(xv.x), x1 = unpackh2(xv.y);
    uint2 o;
    o.x = packh2(a0 + x0.x, a1 + x0.y);
    o.y = packh2(a2 + x1.x, a3 + x1.y);
    ((uint2*)T16)[(size_t)n * 16 + c] = o;
  }
}

// ---- gather2: H2[n] = sig(Q2[n] + sum Q2[src] + bn2); 4 edges/iter ----
__global__ __launch_bounds__(256) void gather2_kernel(
    const unsigned* __restrict__ Q2u, const int* __restrict__ rowptr,
    const int* __restrict__ col, const float* __restrict__ bn2,
    unsigned* __restrict__ H2)
{
  int w = threadIdx.x >> 6, lane = threadIdx.x & 63;
  int n = blockIdx.x * 4 + w;
  if (n >= N_NODES) return;
  int beg = rowptr[n], end = rowptr[n + 1];
  int q = lane >> 4, c = lane & 15;
  const uint2* feat2 = (const uint2*)Q2u;
  float a0 = 0.f, a1 = 0.f, a2 = 0.f, a3 = 0.f;
  for (int k0 = beg; k0 < end; k0 += 64) {
    int kk = k0 + lane;
    int cv = (kk < end) ? col[kk] : 0;
    int m = end - k0; if (m > 64) m = 64;
    int e = 0;
#pragma unroll 2
    for (; e + 3 < m; e += 4) {
      int se = __shfl(cv, e + q);
      uint2 v = feat2[(size_t)se * 16 + c];
      acc4(a0, a1, a2, a3, v);
    }
    int r = m - e;
    if (r) {
      int idx = e + q; if (idx >= m) idx = m - 1;
      int se = __shfl(cv, idx);
      uint2 v = feat2[(size_t)se * 16 + c];
      if (q < r) acc4(a0, a1, a2, a3, v);
    }
  }
  a0 += __shfl_xor(a0, 32); a1 += __shfl_xor(a1, 32);
  a2 += __shfl_xor(a2, 32); a3 += __shfl_xor(a3, 32);
  a0 += __shfl_xor(a0, 16); a1 += __shfl_xor(a1, 16);
  a2 += __shfl_xor(a2, 16); a3 += __shfl_xor(a3, 16);
  if (q == 0) {
    uint2 qv = ((const uint2*)Q2u)[(size_t)n * 16 + c];
    float4 bn = ((const float4*)bn2)[c];
    float2 q0 = unpackh2(qv.x), q1 = unpackh2(qv.y);
    uint2 o;
    o.x = packh2(sigf(a0 + q0.x + bn.x), sigf(a1 + q0.y + bn.y));
    o.y = packh2(sigf(a2 + q1.x + bn.z), sigf(a3 + q1.y + bn.w));
    ((uint2*)H2)[(size_t)n * 16 + c] = o;
  }
}

// ---- gather3 + node3 fused: P3[n] = sig(Q3[n]+agg+bn3) @ Wc3; 8 edges/iter ----
__global__ __launch_bounds__(256) void gather3_kernel(
    const unsigned* __restrict__ Q3u, const int* __restrict__ rowptr,
    const int* __restrict__ col, const float* __restrict__ bn3,
    const float* __restrict__ Wc3, _Float16* __restrict__ P3h)
{
  int w = threadIdx.x >> 6, lane = threadIdx.x & 63;
  int n = blockIdx.x * 4 + w;
  if (n >= N_NODES) return;
  int beg = rowptr[n], end = rowptr[n + 1];
  int q = lane >> 3, c = lane & 7;
  const uint2* feat2 = (const uint2*)Q3u;
  float a0 = 0.f, a1 = 0.f, a2 = 0.f, a3 = 0.f;
  for (int k0 = beg; k0 < end; k0 += 64) {
    int kk = k0 + lane;
    int cv = (kk < end) ? col[kk] : 0;
    int m = end - k0; if (m > 64) m = 64;
    int e = 0;
#pragma unroll 2
    for (; e + 7 < m; e += 8) {
      int se = __shfl(cv, e + q);
      uint2 v = feat2[(size_t)se * 8 + c];
      acc4(a0, a1, a2, a3, v);
    }
    int r = m - e;
    if (r) {
      int idx = e + q; if (idx >= m) idx = m - 1;
      int se = __shfl(cv, idx);
      uint2 v = feat2[(size_t)se * 8 + c];
      if (q < r) acc4(a0, a1, a2, a3, v);
    }
  }
  a0 += __shfl_xor(a0, 32); a1 += __shfl_xor(a1, 32);
  a2 += __shfl_xor(a2, 32); a3 += __shfl_xor(a3, 32);
  a0 += __shfl_xor(a0, 16); a1 += __shfl_xor(a1, 16);
  a2 += __shfl_xor(a2, 16); a3 += __shfl_xor(a3, 16);
  a0 += __shfl_xor(a0, 8);  a1 += __shfl_xor(a1, 8);
  a2 += __shfl_xor(a2, 8);  a3 += __shfl_xor(a3, 8);
  if (q == 0) {   // lanes 0..7: finish node3 dot product
    uint2 qv = ((const uint2*)Q3u)[(size_t)n * 8 + c];
    float4 bn = ((const float4*)bn3)[c];
    float4 wc = ((const float4*)Wc3)[c];
    float2 q0 = unpackh2(qv.x), q1 = unpackh2(qv.y);
    float p = sigf(a0 + q0.x + bn.x) * wc.x + sigf(a1 + q0.y + bn.y) * wc.y
            + sigf(a2 + q1.x + bn.z) * wc.z + sigf(a3 + q1.y + bn.w) * wc.w;
    p += __shfl_xor(p, 1); p += __shfl_xor(p, 2); p += __shfl_xor(p, 4);
    if (c == 0) P3h[n] = (_Float16)p;
  }
}

// ---- node layer 1 (MFMA): T16 (LDS) -> h1 (LDS) -> Q2,P1 (f16) ----
__global__ __launch_bounds__(256) void node1_kernel(
    const unsigned* __restrict__ T16,
    const uint4* __restrict__ Wn1f, const uint4* __restrict__ Wn2f,
    const uint4* __restrict__ Wc1f, const float* __restrict__ bn1,
    _Float16* __restrict__ Q2h, _Float16* __restrict__ P1h)
{
  __shared__ __align__(16) _Float16 t_lds[64 * 72];
  __shared__ __align__(16) _Float16 h1_lds[64 * 136];
  int tid = threadIdx.x;
  int lane = tid & 63, w = tid >> 6;
  int nbase = blockIdx.x * 64;

#pragma unroll
  for (int rep = 0; rep < 2; ++rep) {
    int uidx = rep * 1024 + tid * 4;
    int node = uidx >> 5, c = uidx & 31;
    int gn = nbase + node; if (gn > N_NODES - 1) gn = N_NODES - 1;
    uint4 tv = *(const uint4*)(T16 + (size_t)gn * 32 + c);
    *(uint4*)(t_lds + node * 72 + c * 2) = tv;
  }
  __syncthreads();

  int row16 = lane & 15, chunk = lane >> 4;
  uint4 b1[2][2];
#pragma unroll
  for (int ntl = 0; ntl < 2; ++ntl)
#pragma unroll
    for (int ks = 0; ks < 2; ++ks)
      b1[ntl][ks] = Wn1f[((2 * w + ntl) * 2 + ks) * 64 + lane];

  f32x4 acc[4][2];
#pragma unroll
  for (int mt = 0; mt < 4; ++mt)
#pragma unroll
    for (int ntl = 0; ntl < 2; ++ntl) acc[mt][ntl] = (f32x4){0.f, 0.f, 0.f, 0.f};
#pragma unroll
  for (int mt = 0; mt < 4; ++mt) {
    const _Float16* ab = t_lds + (mt * 16 + row16) * 72 + chunk * 8;
    f16x8 A0 = *(const f16x8*)ab;
    f16x8 A1 = *(const f16x8*)(ab + 32);
#pragma unroll
    for (int ntl = 0; ntl < 2; ++ntl) {
      acc[mt][ntl] = MFMA16(A0, b1[ntl][0], acc[mt][ntl]);
      acc[mt][ntl] = MFMA16(A1, b1[ntl][1], acc[mt][ntl]);
    }
  }
  float bnv0 = bn1[w * 32 + row16], bnv1 = bn1[w * 32 + 16 + row16];
#pragma unroll
  for (int mt = 0; mt < 4; ++mt)
#pragma unroll
    for (int r = 0; r < 4; ++r) {
      int rowl = mt * 16 + chunk * 4 + r;
      h1_lds[rowl * 136 + w * 32 + row16]      = (_Float16)sigf(acc[mt][0][r] + bnv0);
      h1_lds[rowl * 136 + w * 32 + 16 + row16] = (_Float16)sigf(acc[mt][1][r] + bnv1);
    }
  __syncthreads();

#pragma unroll
  for (int job = 0; job < 2; ++job) {
    const uint4* Wf = job ? Wc1f : Wn2f;
    uint4 bf[4];
#pragma unroll
    for (int ks = 0; ks < 4; ++ks) bf[ks] = Wf[(w * 4 + ks) * 64 + lane];
    f32x4 a2[4];
#pragma unroll
    for (int mt = 0; mt < 4; ++mt) a2[mt] = (f32x4){0.f, 0.f, 0.f, 0.f};
#pragma unroll
    for (int mt = 0; mt < 4; ++mt) {
      const _Float16* hb = h1_lds + (mt * 16 + row16) * 136 + chunk * 8;
#pragma unroll
      for (int ks = 0; ks < 4; ++ks) {
        f16x8 A = *(const f16x8*)(hb + ks * 32);
        a2[mt] = MFMA16(A, bf[ks], a2[mt]);
      }
    }
    _Float16* op = job ? P1h : Q2h;
#pragma unroll
    for (int mt = 0; mt < 4; ++mt)
#pragma unroll
      for (int r = 0; r < 4; ++r) {
        int gn = nbase + mt * 16 + chunk * 4 + r;
        if (gn < N_NODES) op[(size_t)gn * 64 + w * 16 + row16] = (_Float16)a2[mt][r];
      }
  }
}

// ---- node layer 2 (MFMA): H2 (LDS copy) -> Q3,P2 (f16) ----
__global__ __launch_bounds__(256) void node2_kernel(
    const unsigned* __restrict__ H2,
    const uint4* __restrict__ Wn3f, const uint4* __restrict__ Wc2f,
    _Float16* __restrict__ Q3h, _Float16* __restrict__ P2h)
{
  __shared__ __align__(16) _Float16 t_lds[64 * 72];
  int tid = threadIdx.x, lane = tid & 63, w = tid >> 6;
  int nbase = blockIdx.x * 64;
#pragma unroll
  for (int rep = 0; rep < 2; ++rep) {
    int uidx = rep * 1024 + tid * 4;
    int node = uidx >> 5, c = uidx & 31;
    int gn = nbase + node; if (gn > N_NODES - 1) gn = N_NODES - 1;
    uint4 tv = *(const uint4*)(H2 + (size_t)gn * 32 + c);
    *(uint4*)(t_lds + node * 72 + c * 2) = tv;
  }
  __syncthreads();
  int row16 = lane & 15, chunk = lane >> 4;
  int mat = w >> 1, nt = w & 1;
  const uint4* Wf = mat ? Wc2f : Wn3f;
  uint4 bf0 = Wf[(nt * 2 + 0) * 64 + lane];
  uint4 bf1 = Wf[(nt * 2 + 1) * 64 + lane];
  f32x4 a2[4];
#pragma unroll
  for (int mt = 0; mt < 4; ++mt) a2[mt] = (f32x4){0.f, 0.f, 0.f, 0.f};
#pragma unroll
  for (int mt = 0; mt < 4; ++mt) {
    const _Float16* ab = t_lds + (mt * 16 + row16) * 72 + chunk * 8;
    f16x8 A0 = *(const f16x8*)ab;
    f16x8 A1 = *(const f16x8*)(ab + 32);
    a2[mt] = MFMA16(A0, bf0, a2[mt]);
    a2[mt] = MFMA16(A1, bf1, a2[mt]);
  }
  _Float16* op = mat ? P2h : Q3h;
#pragma unroll
  for (int mt = 0; mt < 4; ++mt)
#pragma unroll
    for (int r = 0; r < 4; ++r) {
      int gn = nbase + mt * 16 + chunk * 4 + r;
      if (gn < N_NODES) op[(size_t)gn * 32 + nt * 16 + row16] = (_Float16)a2[mt][r];
    }
}

// ---- edge kernel: shuffle-free f16 staging + MFMA GEMV ----
__global__ __launch_bounds__(256) void edge_kernel(
    const int* __restrict__ src, const int* __restrict__ dst,
    const unsigned* __restrict__ P1_16, const unsigned* __restrict__ P2_16,
    const _Float16* __restrict__ P3_16, const uint4* __restrict__ Bfrag,
    const float* __restrict__ bc1, const float* __restrict__ bc2,
    const float* __restrict__ bc3, const float* __restrict__ bg1,
    const float* __restrict__ Wg2, const float* __restrict__ bg2,
    float* __restrict__ out)
{
  __shared__ __align__(16) _Float16 sbuf[4][32 * 104];
  __shared__ int eidx[4][64];
  int lane = threadIdx.x & 63;
  int w = threadIdx.x >> 6;
  int ebase = blockIdx.x * 128 + w * 32;
  _Float16* wb = &sbuf[w][0];

  int e32 = lane & 31;
  const int* bp = (lane < 32) ? src : dst;
  int myi = bp[ebase + e32];
  eidx[w][lane] = myi;

  f16x8 Bf[2][2];
#pragma unroll
  for (int ks = 0; ks < 2; ++ks)
#pragma unroll
    for (int nh = 0; nh < 2; ++nh)
      Bf[ks][nh] = __builtin_bit_cast(f16x8, Bfrag[(ks * 2 + nh) * 64 + lane]);

  {
    float p3v = (float)P3_16[myi];
    float pair = __shfl_xor(p3v, 32);
    if (lane < 32) wb[e32 * 104 + 96] = (_Float16)(p3v + pair);
  }
  {
    int c = lane & 31, half = lane >> 5;
    h2 b1pk = packh2v(bc1[2 * c], bc1[2 * c + 1]);
#pragma unroll
    for (int it = 0; it < 16; ++it) {
      int e = 2 * it + half;
      int s = eidx[w][e];
      int d = eidx[w][32 + e];
      h2 ps = *(const h2*)(P1_16 + (size_t)s * 32 + c);
      h2 pd = *(const h2*)(P1_16 + (size_t)d * 32 + c);
      h2 sum = (ps + pd) + b1pk;
      *(h2*)(wb + e * 104 + 2 * c) = packh2v(sigf((float)sum.x), sigf((float)sum.y));
    }
  }
  {
    int cc = lane & 15, eq = lane >> 4;
    h2 b2pk = packh2v(bc2[2 * cc], bc2[2 * cc + 1]);
#pragma unroll
    for (int it = 0; it < 8; ++it) {
      int e = 4 * it + eq;
      int s = eidx[w][e];
      int d = eidx[w][32 + e];
      h2 ps = *(const h2*)(P2_16 + (size_t)s * 16 + cc);
      h2 pd = *(const h2*)(P2_16 + (size_t)d * 16 + cc);
      h2 sum = (ps + pd) + b2pk;
      *(h2*)(wb + e * 104 + 64 + 2 * cc) = packh2v(sigf((float)sum.x), sigf((float)sum.y));
    }
  }

  int row = lane & 15, chunk = lane >> 4;
  float bg1v0 = bg1[row], bg1v1 = bg1[16 + row];
  float wg2v0 = Wg2[row], wg2v1 = Wg2[16 + row];
  float bg2v = bg2[0], bc3v = bc3[0];
#pragma unroll
  for (int g = 0; g < 2; ++g) {
    const _Float16* abase = wb + (16 * g + row) * 104 + chunk * 8;
    f16x8 A0 = *(const f16x8*)abase;
    f16x8 A1 = *(const f16x8*)(abase + 32);
    f32x4 acc0 = {0.f, 0.f, 0.f, 0.f}, acc1 = {0.f, 0.f, 0.f, 0.f};
    acc0 = __builtin_amdgcn_mfma_f32_16x16x32_f16(A0, Bf[0][0], acc0, 0, 0, 0);
    acc1 = __builtin_amdgcn_mfma_f32_16x16x32_f16(A0, Bf[0][1], acc1, 0, 0, 0);
    acc0 = __builtin_amdgcn_mfma_f32_16x16x32_f16(A1, Bf[1][0], acc0, 0, 0, 0);
    acc1 = __builtin_amdgcn_mfma_f32_16x16x32_f16(A1, Bf[1][1], acc1, 0, 0, 0);
#pragma unroll
    for (int r = 0; r < 4; ++r) {
      int e = 16 * g + chunk * 4 + r;
      float c2a = (float)wb[e * 104 + 64 + row];
      float c2b = (float)wb[e * 104 + 80 + row];
      float v0 = sigf(acc0[r] + bg1v0 + c2a) * wg2v0;
      float v1 = sigf(acc1[r] + bg1v1 + c2b) * wg2v1;
      float part = v0 + v1;
      part += __shfl_xor(part, 1);
      part += __shfl_xor(part, 2);
      part += __shfl_xor(part, 4);
      part += __shfl_xor(part, 8);
      float c3v = (float)wb[e * 104 + 96];
      if (row == 0)
        out[ebase + e] = sigf(part + bg2v + sigf(c3v + bc3v));
    }
  }
}

extern "C" void kernel_launch(void* const* d_in, const int* in_sizes, int n_in,
                              void* d_out, int out_size, void* d_ws, size_t ws_size,
                              hipStream_t stream)
{
  const float* x   = (const float*)d_in[0];
  const int*   src = (const int*)d_in[1];
  const int*   dst = (const int*)d_in[2];
  const float* Wn1 = (const float*)d_in[3];
  const float* bn1 = (const float*)d_in[4];
  const float* Wc1 = (const float*)d_in[5];
  const float* bc1 = (const float*)d_in[6];
  const float* Wn2 = (const float*)d_in[7];
  const float* bn2 = (const float*)d_in[8];
  const float* Wc2 = (const float*)d_in[9];
  const float* bc2 = (const float*)d_in[10];
  const float* Wn3 = (const float*)d_in[11];
  const float* bn3 = (const float*)d_in[12];
  const float* Wc3 = (const float*)d_in[13];
  const float* bc3 = (const float*)d_in[14];
  const float* Wg1 = (const float*)d_in[15];
  const float* bg1 = (const float*)d_in[16];
  const float* Wg2 = (const float*)d_in[17];
  const float* bg2 = (const float*)d_in[18];
  float* out = (float*)d_out;

  char* base = (char*)d_ws;
  unsigned* TMP16 = (unsigned*)base; base += (size_t)N_NODES * 32 * 4;   // T16 / H2
  unsigned* X16   = (unsigned*)base; base += (size_t)N_NODES * 32 * 4;
  unsigned* Q2_16 = (unsigned*)base; base += (size_t)N_NODES * 32 * 4;
  unsigned* P1_16 = (unsigned*)base; base += (size_t)N_NODES * 32 * 4;
  unsigned* Q3_16 = (unsigned*)base; base += (size_t)N_NODES * 16 * 4;
  unsigned* P2_16 = (unsigned*)base; base += (size_t)N_NODES * 16 * 4;
  _Float16* P3_16 = (_Float16*)base; base += ((size_t)N_NODES * 2 + 15) / 16 * 16;
  int* rowptr = (int*)base;          base += (size_t)(N_NODES + 1) * 4;
  int* cursor = (int*)base;          base += (size_t)N_NODES * 4;
  int* col    = (int*)base;          base += (size_t)N_EDGES * 4;
  int* bsum   = (int*)base;          base += (size_t)NBLK_SCAN * 4 + 12;
  uint4* Wg1f = (uint4*)base;        base += 4 * 64 * 16;
  uint4* Wn1f = (uint4*)base;        base += 16 * 64 * 16;
  uint4* Wn2f = (uint4*)base;        base += 16 * 64 * 16;
  uint4* Wc1f = (uint4*)base;        base += 16 * 64 * 16;
  uint4* Wn3f = (uint4*)base;        base += 4 * 64 * 16;
  uint4* Wc2f = (uint4*)base;        base += 4 * 64 * 16;

  // prep (cvt + hist + frag-pack) and CSR build
  hipMemsetAsync(cursor, 0, (size_t)N_NODES * sizeof(int), stream);
  prep_kernel<<<CVT_B + HIST_B + 1, 256, 0, stream>>>(x, X16, dst, cursor,
      Wn1, Wn2, Wc1, Wn3, Wc2, Wg1, Wn1f, Wn2f, Wc1f, Wn3f, Wc2f, Wg1f);
  scan1_kernel<<<NBLK_SCAN, 256, 0, stream>>>(cursor, bsum);
  scan2_kernel<<<1, 256, 0, stream>>>(bsum);
  scan3_kernel<<<NBLK_SCAN, 256, 0, stream>>>(cursor, bsum, rowptr, cursor);
  fill_kernel<<<HIST_B, 256, 0, stream>>>(src, dst, cursor, col);

  // layer 1: T16 = x + agg(x); node1 -> Q2, P1
  gather1_kernel<<<(N_NODES + 3) / 4, 256, 0, stream>>>(X16, rowptr, col, TMP16);
  node1_kernel<<<NODE_B, 256, 0, stream>>>(TMP16, Wn1f, Wn2f, Wc1f, bn1,
      (_Float16*)Q2_16, (_Float16*)P1_16);
  // layer 2: H2 = sig(Q2 + agg(Q2) + bn2); node2 -> Q3, P2
  gather2_kernel<<<(N_NODES + 3) / 4, 256, 0, stream>>>(Q2_16, rowptr, col, bn2, TMP16);
  node2_kernel<<<NODE_B, 256, 0, stream>>>(TMP16, Wn3f, Wc2f,
      (_Float16*)Q3_16, (_Float16*)P2_16);
  // layer 3 (gather + node3 fused) -> P3
  gather3_kernel<<<(N_NODES + 3) / 4, 256, 0, stream>>>(Q3_16, rowptr, col, bn3, Wc3, P3_16);
  // edge-level epilogue
  edge_kernel<<<N_EDGES / 128, 256, 0, stream>>>(src, dst, P1_16, P2_16, P3_16, Wg1f,
      bc1, bc2, bc3, bg1, Wg2, bg2, out);
}